// Round 3
// baseline (1286.862 us; speedup 1.0000x reference)
//
#include <hip/hip_runtime.h>
#include <math.h>

// YIN pitch, MI355X. Constants from reference:
//   SR=16000, STRIDES=160, W=257, TAU_MAX=213, TAU_MIN=26, C=187, MEDIAN=30
#define T_LEN    160000
#define STRIDES  160
#define NF       1001
#define NB       64
#define W_LEN    257
#define TAU_MINC 26
#define C_LEN    187
#define NFRAMES  (NB * NF)     // 64064

// Per-wave LDS region: chunk-padded layout. slot(C) = C + (C>>3) spreads the
// stride-16-element (64B) access patterns across bank-quads while preserving
// 16B alignment of float4 chunks. Region = 296 chunk-slots = 1184 floats.
#define REG_F    1184
#define CM_BASE  320           // element base of cmnd array (chunk 80)

__device__ __forceinline__ int slotE(int E) {   // padded float index (E = element)
    int C = E >> 2;
    return ((C + (C >> 3)) << 2) | (E & 3);
}
__device__ __forceinline__ int slotC(int C) {   // padded float index of chunk start
    return (C + (C >> 3)) << 2;
}

__global__ __launch_bounds__(256, 4) void yin_frames(const float* __restrict__ in,
                                                     float* __restrict__ pitch) {
    __shared__ float R_[4][REG_F];

    const int wid  = threadIdx.x >> 6;
    const int lane = threadIdx.x & 63;
    const int frame = blockIdx.x * 4 + wid;
    const int b = frame / NF;
    const int f = frame - b * NF;
    float* R = R_[wid];

    // ---------------- phase 1: zero-fill pad region + stage frame ----------------
    // zero raw floats [288, 580)  (covers padded slots of elements 256..539)
    float4 z4; z4.x = 0.f; z4.y = 0.f; z4.z = 0.f; z4.w = 0.f;
    *(float4*)(R + 288 + 4 * lane) = z4;
    if (lane < 9) *(float4*)(R + 544 + 4 * lane) = z4;

    const float* src = in + (size_t)b * T_LEN;
    const int start = f * STRIDES;
    int e0 = start + 4 * lane;
    float4 q;
    if (e0 + 3 < T_LEN) {
        q = *(const float4*)(src + e0);
    } else {
        q.x = (e0 + 0 < T_LEN) ? src[e0 + 0] : 0.f;
        q.y = (e0 + 1 < T_LEN) ? src[e0 + 1] : 0.f;
        q.z = (e0 + 2 < T_LEN) ? src[e0 + 2] : 0.f;
        q.w = (e0 + 3 < T_LEN) ? src[e0 + 3] : 0.f;
    }
    *(float4*)(R + slotE(4 * lane)) = q;      // elements 4l..4l+3 (slots < 288)
    if (lane == 0) {
        int e2 = start + 256;
        R[slotE(256)] = (e2 < T_LEN) ? src[e2] : 0.f;
    }

    // ---------------- phase 2: cumsum of squares (wave scan, in regs) ------------
    float p0 = q.x * q.x;
    float p1 = p0 + q.y * q.y;
    float p2 = p1 + q.z * q.z;
    float p3 = p2 + q.w * q.w;
    float sc = p3;
#pragma unroll
    for (int off = 1; off < 64; off <<= 1) {
        float o = __shfl_up(sc, off);
        if (lane >= off) sc += o;
    }
    float base = sc - p3;
    float4 csv;
    csv.x = base + p0; csv.y = base + p1; csv.z = base + p2; csv.w = base + p3;
    float s256 = R[slotE(256)];               // broadcast (same-wave write visible)
    float totE = __shfl(sc, 63) + s256 * s256;

    // ---------------- phase 3: autocorrelation, K-split 4 x 16-tau blocking ------
    // lane = (g,i): g = lane>>6... g = lane>>4 covers j in [64g,64g+64); i = lane&15
    // covers taus 16i..16i+15. 20-float rolling register window; indices are
    // FORCED compile-time static via 16 literal STEP(T) macro expansions
    // (R2 lesson: #pragma unroll on the 1024-FMA outer loop was refused by the
    // compiler -> runtime %20 indexing -> scratch spill -> 6 GB HBM traffic).
    const int g  = lane >> 4;
    const int ii = lane & 15;
    const int Ebase = (g << 6) + (ii << 4);   // 64g + 16i

    float acc[16];
#pragma unroll
    for (int k = 0; k < 16; ++k) acc[k] = 0.0f;

    float w[20];
#pragma unroll
    for (int k = 0; k < 5; ++k) {
        float4 t4 = *(const float4*)(R + slotE(Ebase + 4 * k));
        w[4 * k + 0] = t4.x; w[4 * k + 1] = t4.y; w[4 * k + 2] = t4.z; w[4 * k + 3] = t4.w;
    }
    float4 cq = *(const float4*)(R + slotE(g << 6));

#define YIN_STEP(T)                                                              \
    {                                                                            \
        const float cc0 = cq.x, cc1 = cq.y, cc2 = cq.z, cc3 = cq.w;              \
        float4 nw, nc;                                                           \
        if ((T) < 15) {                                                          \
            nw = *(const float4*)(R + slotE(Ebase + 4 * (T) + 20));              \
            nc = *(const float4*)(R + slotE((g << 6) + 4 * (T) + 4));            \
        }                                                                        \
        _Pragma("unroll")                                                        \
        for (int tt = 0; tt < 16; ++tt) {                                        \
            acc[tt] = fmaf(cc0, w[(4 * (T) + 0 + tt) % 20], acc[tt]);            \
            acc[tt] = fmaf(cc1, w[(4 * (T) + 1 + tt) % 20], acc[tt]);            \
            acc[tt] = fmaf(cc2, w[(4 * (T) + 2 + tt) % 20], acc[tt]);            \
            acc[tt] = fmaf(cc3, w[(4 * (T) + 3 + tt) % 20], acc[tt]);            \
        }                                                                        \
        if ((T) < 15) {                                                          \
            const int wb = (4 * (T)) % 20;                                       \
            w[wb + 0] = nw.x; w[wb + 1] = nw.y;                                  \
            w[wb + 2] = nw.z; w[wb + 3] = nw.w;                                  \
            cq = nc;                                                             \
        }                                                                        \
    }

    YIN_STEP(0)  YIN_STEP(1)  YIN_STEP(2)  YIN_STEP(3)
    YIN_STEP(4)  YIN_STEP(5)  YIN_STEP(6)  YIN_STEP(7)
    YIN_STEP(8)  YIN_STEP(9)  YIN_STEP(10) YIN_STEP(11)
    YIN_STEP(12) YIN_STEP(13) YIN_STEP(14) YIN_STEP(15)
#undef YIN_STEP

    // ---------------- phase 4: reduce partials over g (LDS round-trip) -----------
    // part[g][tau], chunk index = 66g + 4i + q. Aliases the s region (s is dead).
#pragma unroll
    for (int q4 = 0; q4 < 4; ++q4) {
        float4 v4;
        v4.x = acc[4 * q4 + 0]; v4.y = acc[4 * q4 + 1];
        v4.z = acc[4 * q4 + 2]; v4.w = acc[4 * q4 + 3];
        *(float4*)(R + slotC(g * 66 + ii * 4 + q4)) = v4;
    }
    float a0 = 0.f, a1 = 0.f, a2 = 0.f, a3 = 0.f;
#pragma unroll
    for (int gg = 0; gg < 4; ++gg) {
        float4 p4 = *(const float4*)(R + slotC(gg * 66 + lane));
        a0 += p4.x; a1 += p4.y; a2 += p4.z; a3 += p4.w;
    }
    // lane now owns corr[4l..4l+3]

    // ---------------- phase 5: CMND (4-tau/lane layout) --------------------------
    *(float4*)(R + slotE(4 * lane)) = csv;    // cs[e], aliases part[g=0] (dead)
    if (lane == 0) R[slotE(256)] = totE;
    float4 csr  = *(const float4*)(R + slotE(252 - 4 * lane));
    float csTop = R[slotE(256 - 4 * lane)];

    float d0 = csTop - 2.0f * a0 + totE - csv.x;
    float d1 = csr.w - 2.0f * a1 + totE - csv.y;
    float d2 = csr.z - 2.0f * a2 + totE - csv.z;
    float d3 = csr.y - 2.0f * a3 + totE - csv.w;
    if (lane == 0) d0 = 0.0f;                 // diff[0] excluded from prefix
    float l0 = d0, l1 = l0 + d1, l2 = l1 + d2, l3 = l2 + d3;
    float scn = l3;
#pragma unroll
    for (int off = 1; off < 64; off <<= 1) {
        float o = __shfl_up(scn, off);
        if (lane >= off) scn += o;
    }
    float pb = scn - l3;
    const int t0 = 4 * lane;
    float cd0 = d0 * (float)(t0 + 0) / (pb + l0 + 1e-7f);
    float cd1 = d1 * (float)(t0 + 1) / (pb + l1 + 1e-7f);
    float cd2 = d2 * (float)(t0 + 2) / (pb + l2 + 1e-7f);
    float cd3 = d3 * (float)(t0 + 3) / (pb + l3 + 1e-7f);
    if (lane <= 53) {                          // taus 0..215 (>=213 junk, never read)
        float4 cdv;
        cdv.x = (lane == 0) ? 1.0f : cd0;
        cdv.y = cd1; cdv.z = cd2; cdv.w = cd3;
        *(float4*)(R + slotE(CM_BASE + t0)) = cdv;
    }

    // ---------------- phase 6: threshold + tau searches via ballot ---------------
    // cmnd[i] = R[CM_BASE + 26 + i], i in [0,187)
    float am[3], bm[3], cm3[3];
#pragma unroll
    for (int r = 0; r < 3; ++r) {
        int i = r * 64 + lane;
        am[r]  = R[slotE(CM_BASE + 25 + i)];   // cmnd[i-1] (junk @ i=0, masked)
        bm[r]  = R[slotE(CM_BASE + 26 + i)];   // cmnd[i]
        cm3[r] = R[slotE(CM_BASE + 27 + i)];   // cmnd[i+1] (junk @ i=186, masked)
    }
    unsigned long long tm0 = __ballot((lane < 187)       && (bm[0] < 0.1f));
    unsigned long long tm1 = __ballot((64 + lane < 187)  && (bm[1] < 0.1f));
    unsigned long long tm2 = __ballot((128 + lane < 187) && (bm[2] < 0.1f));
    int cand = tm0 ? (__ffsll(tm0) - 1)
             : (tm1 ? (64 + __ffsll(tm1) - 1)
             : (tm2 ? (128 + __ffsll(tm2) - 1) : 999));
    const int thold = (cand == 0 || cand == 999) ? C_LEN : cand;

    unsigned long long lm[3];
#pragma unroll
    for (int r = 0; r < 3; ++r) {
        int i = r * 64 + lane;
        bool left  = (i == 0)   || (bm[r] - am[r] <= 0.0f);
        bool right = (i == 186) || (cm3[r] - bm[r] >= 0.0f);
        lm[r] = __ballot((i >= thold) && (i < C_LEN) && left && right);
    }
    int tcand = lm[0] ? (__ffsll(lm[0]) - 1)
              : (lm[1] ? (64 + __ffsll(lm[1]) - 1)
              : (lm[2] ? (128 + __ffsll(lm[2]) - 1) : 999));
    const int tau = (tcand == 999) ? 0 : tcand;

    // ---------------- phase 7: parabolic interp + pitch --------------------------
    float pv = 0.0f;
    if (tau > 0) {
        float shift = 0.0f;
        if (tau <= C_LEN - 2) {
            float pp = R[slotE(CM_BASE + 26 + tau - 1)];
            float cc = R[slotE(CM_BASE + 26 + tau)];
            float nn = R[slotE(CM_BASE + 26 + tau + 1)];
            float aa = nn + pp - 2.0f * cc;
            float bb = 0.5f * (nn - pp);
            shift = (fabsf(bb) >= fabsf(aa)) ? 0.0f : (-bb / aa);
        }
        pv = 16000.0f / ((float)(tau + TAU_MINC + 1) + shift);
    }
    if (lane == 0) pitch[frame] = pv;
}

// 30-wide median (index 14 of ascending sort), edge-padded (15,14)
__global__ __launch_bounds__(256) void median_k(const float* __restrict__ pitch,
                                                float* __restrict__ out) {
    int idx = blockIdx.x * blockDim.x + threadIdx.x;
    if (idx >= NFRAMES) return;
    int b = idx / NF;
    int f = idx - b * NF;
    const float* p = pitch + b * NF;
    float v[30];
#pragma unroll
    for (int k = 0; k < 30; ++k) {
        int j = f + k - 15;
        j = (j < 0) ? 0 : ((j > NF - 1) ? NF - 1 : j);
        v[k] = p[j];
    }
    float result = 0.0f;
#pragma unroll 1
    for (int i = 0; i < 30; ++i) {
        int lt = 0, le = 0;
#pragma unroll
        for (int j = 0; j < 30; ++j) {
            lt += (v[j] < v[i]);
            le += (v[j] <= v[i]);
        }
        if (lt <= 14 && 14 < le) result = v[i];
    }
    out[idx] = result;
}

extern "C" void kernel_launch(void* const* d_in, const int* in_sizes, int n_in,
                              void* d_out, int out_size, void* d_ws, size_t ws_size,
                              hipStream_t stream) {
    (void)in_sizes; (void)n_in; (void)out_size; (void)ws_size;
    const float* in = (const float*)d_in[0];
    float* out = (float*)d_out;
    float* pitch = (float*)d_ws;     // NFRAMES floats = 256 KB scratch

    yin_frames<<<NFRAMES / 4, 256, 0, stream>>>(in, pitch);
    median_k<<<(NFRAMES + 255) / 256, 256, 0, stream>>>(pitch, out);
}

// Round 4
// 1283.757 us; speedup vs baseline: 1.0024x; 1.0024x over previous
//
#include <hip/hip_runtime.h>
#include <math.h>

// YIN pitch, MI355X. Constants from reference:
//   SR=16000, STRIDES=160, W=257, TAU_MAX=213, TAU_MIN=26, C=187, MEDIAN=30
#define T_LEN    160000
#define STRIDES  160
#define NF       1001
#define NB       64
#define W_LEN    257
#define TAU_MINC 26
#define C_LEN    187
#define NFRAMES  (NB * NF)     // 64064

// Per-wave LDS region: chunk-padded layout. slot(C) = C + (C>>3) spreads the
// stride-16-element (64B) access patterns across bank-quads while preserving
// 16B alignment of float4 chunks. Region = 296 chunk-slots = 1184 floats.
#define REG_F    1184
#define CM_BASE  320           // element base of cmnd array (chunk 80)

__device__ __forceinline__ int slotE(int E) {   // padded float index (E = element)
    int C = E >> 2;
    return ((C + (C >> 3)) << 2) | (E & 3);
}
__device__ __forceinline__ int slotC(int C) {   // padded float index of chunk start
    return (C + (C >> 3)) << 2;
}

__global__ __launch_bounds__(256, 4) void yin_frames(const float* __restrict__ in,
                                                     float* __restrict__ pitch) {
    __shared__ float R_[4][REG_F];

    const int wid  = threadIdx.x >> 6;
    const int lane = threadIdx.x & 63;
    const int frame = blockIdx.x * 4 + wid;
    const int b = frame / NF;
    const int f = frame - b * NF;
    float* R = R_[wid];

    // ---------------- phase 1: zero-fill pad region + stage frame ----------------
    // zero raw slots [288, 580) == padded slots of elements 256..515 (max read 515)
    float4 z4; z4.x = 0.f; z4.y = 0.f; z4.z = 0.f; z4.w = 0.f;
    *(float4*)(R + 288 + 4 * lane) = z4;
    if (lane < 9) *(float4*)(R + 544 + 4 * lane) = z4;

    const float* src = in + (size_t)b * T_LEN;
    const int start = f * STRIDES;
    int e0 = start + 4 * lane;
    float4 q;
    if (e0 + 3 < T_LEN) {
        q = *(const float4*)(src + e0);
    } else {
        q.x = (e0 + 0 < T_LEN) ? src[e0 + 0] : 0.f;
        q.y = (e0 + 1 < T_LEN) ? src[e0 + 1] : 0.f;
        q.z = (e0 + 2 < T_LEN) ? src[e0 + 2] : 0.f;
        q.w = (e0 + 3 < T_LEN) ? src[e0 + 3] : 0.f;
    }
    *(float4*)(R + slotE(4 * lane)) = q;      // elements 4l..4l+3 (slots < 288)
    if (lane == 0) {
        int e2 = start + 256;
        R[slotE(256)] = (e2 < T_LEN) ? src[e2] : 0.f;
    }

    // ---------------- phase 2: cumsum of squares (wave scan, in regs) ------------
    float p0 = q.x * q.x;
    float p1 = p0 + q.y * q.y;
    float p2 = p1 + q.z * q.z;
    float p3 = p2 + q.w * q.w;
    float sc = p3;
#pragma unroll
    for (int off = 1; off < 64; off <<= 1) {
        float o = __shfl_up(sc, off);
        if (lane >= off) sc += o;
    }
    float base = sc - p3;
    float4 csv;
    csv.x = base + p0; csv.y = base + p1; csv.z = base + p2; csv.w = base + p3;
    float s256 = R[slotE(256)];               // broadcast (same-wave write visible)
    float totE = __shfl(sc, 63) + s256 * s256;

    // ---------------- phase 3: autocorrelation, K-split 4 x 16-tau blocking ------
    // lane = (g,i): g = lane>>4 covers j in [64g,64g+64); i = lane&15 covers taus
    // 16i..16i+15. 20-float rolling register window.
    // R2/R3 lesson: SROA runs BEFORE loop unrolling, so ANY loop-variable index
    // into w[]/acc[] demotes them to scratch (6 GB HBM traffic). Both loop levels
    // are therefore expanded via nested macros -> every index is an integer
    // constant expression at parse time.
    const int g  = lane >> 4;
    const int ii = lane & 15;
    const int Ebase = (g << 6) + (ii << 4);   // 64g + 16i

    float acc[16];
#pragma unroll
    for (int k = 0; k < 16; ++k) acc[k] = 0.0f;

    float w[20];
#pragma unroll
    for (int k = 0; k < 5; ++k) {
        float4 t4 = *(const float4*)(R + slotE(Ebase + 4 * k));
        w[4 * k + 0] = t4.x; w[4 * k + 1] = t4.y; w[4 * k + 2] = t4.z; w[4 * k + 3] = t4.w;
    }
    float4 cq = *(const float4*)(R + slotE(g << 6));

#define YIN_TT(T, TT)                                                            \
    acc[TT] = fmaf(cc0, w[(4 * (T) + 0 + (TT)) % 20], acc[TT]);                  \
    acc[TT] = fmaf(cc1, w[(4 * (T) + 1 + (TT)) % 20], acc[TT]);                  \
    acc[TT] = fmaf(cc2, w[(4 * (T) + 2 + (TT)) % 20], acc[TT]);                  \
    acc[TT] = fmaf(cc3, w[(4 * (T) + 3 + (TT)) % 20], acc[TT]);

#define YIN_ALLTT(T)                                                             \
    YIN_TT(T, 0)  YIN_TT(T, 1)  YIN_TT(T, 2)  YIN_TT(T, 3)                       \
    YIN_TT(T, 4)  YIN_TT(T, 5)  YIN_TT(T, 6)  YIN_TT(T, 7)                       \
    YIN_TT(T, 8)  YIN_TT(T, 9)  YIN_TT(T, 10) YIN_TT(T, 11)                      \
    YIN_TT(T, 12) YIN_TT(T, 13) YIN_TT(T, 14) YIN_TT(T, 15)

#define YIN_STEP(T)                                                              \
    {                                                                            \
        const float cc0 = cq.x, cc1 = cq.y, cc2 = cq.z, cc3 = cq.w;              \
        float4 nw, nc;                                                           \
        if ((T) < 15) {                                                          \
            nw = *(const float4*)(R + slotE(Ebase + 4 * (T) + 20));              \
            nc = *(const float4*)(R + slotE((g << 6) + 4 * (T) + 4));            \
        }                                                                        \
        YIN_ALLTT(T)                                                             \
        if ((T) < 15) {                                                          \
            w[(4 * (T) + 0) % 20] = nw.x; w[(4 * (T) + 1) % 20] = nw.y;          \
            w[(4 * (T) + 2) % 20] = nw.z; w[(4 * (T) + 3) % 20] = nw.w;          \
            cq = nc;                                                             \
        }                                                                        \
    }

    YIN_STEP(0)  YIN_STEP(1)  YIN_STEP(2)  YIN_STEP(3)
    YIN_STEP(4)  YIN_STEP(5)  YIN_STEP(6)  YIN_STEP(7)
    YIN_STEP(8)  YIN_STEP(9)  YIN_STEP(10) YIN_STEP(11)
    YIN_STEP(12) YIN_STEP(13) YIN_STEP(14) YIN_STEP(15)
#undef YIN_STEP
#undef YIN_ALLTT
#undef YIN_TT

    // ---------------- phase 4: reduce partials over g (LDS round-trip) -----------
    // part[g][tau], chunk index = 66g + 4i + q. Aliases the s region (s is dead).
    {
        float4 v4;
        v4.x = acc[0];  v4.y = acc[1];  v4.z = acc[2];  v4.w = acc[3];
        *(float4*)(R + slotC(g * 66 + ii * 4 + 0)) = v4;
        v4.x = acc[4];  v4.y = acc[5];  v4.z = acc[6];  v4.w = acc[7];
        *(float4*)(R + slotC(g * 66 + ii * 4 + 1)) = v4;
        v4.x = acc[8];  v4.y = acc[9];  v4.z = acc[10]; v4.w = acc[11];
        *(float4*)(R + slotC(g * 66 + ii * 4 + 2)) = v4;
        v4.x = acc[12]; v4.y = acc[13]; v4.z = acc[14]; v4.w = acc[15];
        *(float4*)(R + slotC(g * 66 + ii * 4 + 3)) = v4;
    }
    float a0, a1, a2, a3;
    {
        float4 u0 = *(const float4*)(R + slotC(0 * 66 + lane));
        float4 u1 = *(const float4*)(R + slotC(1 * 66 + lane));
        float4 u2 = *(const float4*)(R + slotC(2 * 66 + lane));
        float4 u3 = *(const float4*)(R + slotC(3 * 66 + lane));
        a0 = (u0.x + u1.x) + (u2.x + u3.x);
        a1 = (u0.y + u1.y) + (u2.y + u3.y);
        a2 = (u0.z + u1.z) + (u2.z + u3.z);
        a3 = (u0.w + u1.w) + (u2.w + u3.w);
    }
    // lane now owns corr[4l..4l+3]

    // ---------------- phase 5: CMND (4-tau/lane layout) --------------------------
    *(float4*)(R + slotE(4 * lane)) = csv;    // cs[e], aliases part (dead)
    if (lane == 0) R[slotE(256)] = totE;
    float4 csr  = *(const float4*)(R + slotE(252 - 4 * lane));
    float csTop = R[slotE(256 - 4 * lane)];

    float d0 = csTop - 2.0f * a0 + totE - csv.x;
    float d1 = csr.w - 2.0f * a1 + totE - csv.y;
    float d2 = csr.z - 2.0f * a2 + totE - csv.z;
    float d3 = csr.y - 2.0f * a3 + totE - csv.w;
    if (lane == 0) d0 = 0.0f;                 // diff[0] excluded from prefix
    float l0 = d0, l1 = l0 + d1, l2 = l1 + d2, l3 = l2 + d3;
    float scn = l3;
#pragma unroll
    for (int off = 1; off < 64; off <<= 1) {
        float o = __shfl_up(scn, off);
        if (lane >= off) scn += o;
    }
    float pb = scn - l3;
    const int t0 = 4 * lane;
    float cd0 = d0 * (float)(t0 + 0) / (pb + l0 + 1e-7f);
    float cd1 = d1 * (float)(t0 + 1) / (pb + l1 + 1e-7f);
    float cd2 = d2 * (float)(t0 + 2) / (pb + l2 + 1e-7f);
    float cd3 = d3 * (float)(t0 + 3) / (pb + l3 + 1e-7f);
    if (lane <= 53) {                          // taus 0..215 (>=213 junk, never read)
        float4 cdv;
        cdv.x = (lane == 0) ? 1.0f : cd0;
        cdv.y = cd1; cdv.z = cd2; cdv.w = cd3;
        *(float4*)(R + slotE(CM_BASE + t0)) = cdv;
    }

    // ---------------- phase 6: threshold + tau searches via ballot ---------------
    // cmnd[i] = R[CM_BASE + 26 + i], i in [0,187). Fully hand-expanded (no arrays).
    const float am0  = R[slotE(CM_BASE + 25 + lane)];
    const float bm0  = R[slotE(CM_BASE + 26 + lane)];
    const float cn0  = R[slotE(CM_BASE + 27 + lane)];
    const float am1  = R[slotE(CM_BASE + 25 + 64 + lane)];
    const float bm1  = R[slotE(CM_BASE + 26 + 64 + lane)];
    const float cn1  = R[slotE(CM_BASE + 27 + 64 + lane)];
    const float am2  = R[slotE(CM_BASE + 25 + 128 + lane)];
    const float bm2  = R[slotE(CM_BASE + 26 + 128 + lane)];
    const float cn2  = R[slotE(CM_BASE + 27 + 128 + lane)];

    unsigned long long tm0 = __ballot((lane < 187)       && (bm0 < 0.1f));
    unsigned long long tm1 = __ballot((64 + lane < 187)  && (bm1 < 0.1f));
    unsigned long long tm2 = __ballot((128 + lane < 187) && (bm2 < 0.1f));
    int cand = tm0 ? (__ffsll(tm0) - 1)
             : (tm1 ? (64 + __ffsll(tm1) - 1)
             : (tm2 ? (128 + __ffsll(tm2) - 1) : 999));
    const int thold = (cand == 0 || cand == 999) ? C_LEN : cand;

    const int i0 = lane, i1 = 64 + lane, i2 = 128 + lane;
    bool L0 = (i0 == 0)   || (bm0 - am0 <= 0.0f);
    bool R0 = (i0 == 186) || (cn0 - bm0 >= 0.0f);
    bool L1 = (bm1 - am1 <= 0.0f);
    bool R1 = (cn1 - bm1 >= 0.0f);
    bool L2 = (bm2 - am2 <= 0.0f);
    bool R2 = (i2 == 186) || (cn2 - bm2 >= 0.0f);
    unsigned long long lm0 = __ballot((i0 >= thold) && (i0 < C_LEN) && L0 && R0);
    unsigned long long lm1 = __ballot((i1 >= thold) && (i1 < C_LEN) && L1 && R1);
    unsigned long long lm2 = __ballot((i2 >= thold) && (i2 < C_LEN) && L2 && R2);
    int tcand = lm0 ? (__ffsll(lm0) - 1)
              : (lm1 ? (64 + __ffsll(lm1) - 1)
              : (lm2 ? (128 + __ffsll(lm2) - 1) : 999));
    const int tau = (tcand == 999) ? 0 : tcand;

    // ---------------- phase 7: parabolic interp + pitch --------------------------
    float pv = 0.0f;
    if (tau > 0) {
        float shift = 0.0f;
        if (tau <= C_LEN - 2) {
            float pp = R[slotE(CM_BASE + 26 + tau - 1)];
            float cc = R[slotE(CM_BASE + 26 + tau)];
            float nn = R[slotE(CM_BASE + 26 + tau + 1)];
            float aa = nn + pp - 2.0f * cc;
            float bb = 0.5f * (nn - pp);
            shift = (fabsf(bb) >= fabsf(aa)) ? 0.0f : (-bb / aa);
        }
        pv = 16000.0f / ((float)(tau + TAU_MINC + 1) + shift);
    }
    if (lane == 0) pitch[frame] = pv;
}

// 30-wide median (index 14 of ascending sort), edge-padded (15,14)
__global__ __launch_bounds__(256) void median_k(const float* __restrict__ pitch,
                                                float* __restrict__ out) {
    int idx = blockIdx.x * blockDim.x + threadIdx.x;
    if (idx >= NFRAMES) return;
    int b = idx / NF;
    int f = idx - b * NF;
    const float* p = pitch + b * NF;
    float v[30];
#pragma unroll
    for (int k = 0; k < 30; ++k) {
        int j = f + k - 15;
        j = (j < 0) ? 0 : ((j > NF - 1) ? NF - 1 : j);
        v[k] = p[j];
    }
    float result = 0.0f;
#pragma unroll 1
    for (int i = 0; i < 30; ++i) {
        int lt = 0, le = 0;
#pragma unroll
        for (int j = 0; j < 30; ++j) {
            lt += (v[j] < v[i]);
            le += (v[j] <= v[i]);
        }
        if (lt <= 14 && 14 < le) result = v[i];
    }
    out[idx] = result;
}

extern "C" void kernel_launch(void* const* d_in, const int* in_sizes, int n_in,
                              void* d_out, int out_size, void* d_ws, size_t ws_size,
                              hipStream_t stream) {
    (void)in_sizes; (void)n_in; (void)out_size; (void)ws_size;
    const float* in = (const float*)d_in[0];
    float* out = (float*)d_out;
    float* pitch = (float*)d_ws;     // NFRAMES floats = 256 KB scratch

    yin_frames<<<NFRAMES / 4, 256, 0, stream>>>(in, pitch);
    median_k<<<(NFRAMES + 255) / 256, 256, 0, stream>>>(pitch, out);
}

// Round 5
// 159.264 us; speedup vs baseline: 8.0801x; 8.0606x over previous
//
#include <hip/hip_runtime.h>
#include <math.h>

// YIN pitch, MI355X. Constants from reference:
//   SR=16000, STRIDES=160, W=257, TAU_MAX=213, TAU_MIN=26, C=187, MEDIAN=30
#define T_LEN    160000
#define STRIDES  160
#define NF       1001
#define NB       64
#define W_LEN    257
#define TAU_MINC 26
#define C_LEN    187
#define NFRAMES  (NB * NF)     // 64064

// Per-wave LDS region: chunk-padded layout. slot(C) = C + (C>>3) spreads the
// stride-16-element (64B) access patterns across bank-quads while preserving
// 16B alignment of float4 chunks. Region = 296 chunk-slots = 1184 floats.
#define REG_F    1184
#define CM_BASE  320           // element base of cmnd array (chunk 80)

__device__ __forceinline__ int slotE(int E) {   // padded float index (E = element)
    int C = E >> 2;
    return ((C + (C >> 3)) << 2) | (E & 3);
}
__device__ __forceinline__ int slotC(int C) {   // padded float index of chunk start
    return (C + (C >> 3)) << 2;
}

// R2-R4 lesson: float w[20]/acc[16] allocas survive SROA (too many uses in one
// straight-line block), land in scratch -> 6 GB HBM traffic, 7x regression.
// This version uses ONLY named scalars in the hot loop - nothing indexable.

__global__ __launch_bounds__(256) void yin_frames(const float* __restrict__ in,
                                                  float* __restrict__ pitch) {
    __shared__ float R_[4][REG_F];

    const int wid  = threadIdx.x >> 6;
    const int lane = threadIdx.x & 63;
    const int frame = blockIdx.x * 4 + wid;
    const int b = frame / NF;
    const int f = frame - b * NF;
    float* R = R_[wid];

    // ---------------- phase 1: zero-fill pad region + stage frame ----------------
    // zero raw slots [288, 580): padded slots of elements 256..515 (max read 511)
    float4 z4; z4.x = 0.f; z4.y = 0.f; z4.z = 0.f; z4.w = 0.f;
    *(float4*)(R + 288 + 4 * lane) = z4;
    if (lane < 9) *(float4*)(R + 544 + 4 * lane) = z4;

    const float* src = in + (size_t)b * T_LEN;
    const int start = f * STRIDES;
    int e0 = start + 4 * lane;
    float4 q;
    if (e0 + 3 < T_LEN) {
        q = *(const float4*)(src + e0);
    } else {
        q.x = (e0 + 0 < T_LEN) ? src[e0 + 0] : 0.f;
        q.y = (e0 + 1 < T_LEN) ? src[e0 + 1] : 0.f;
        q.z = (e0 + 2 < T_LEN) ? src[e0 + 2] : 0.f;
        q.w = (e0 + 3 < T_LEN) ? src[e0 + 3] : 0.f;
    }
    *(float4*)(R + slotE(4 * lane)) = q;      // elements 4l..4l+3 (slots < 288)
    if (lane == 0) {
        int e2 = start + 256;
        R[slotE(256)] = (e2 < T_LEN) ? src[e2] : 0.f;
    }

    // ---------------- phase 2: cumsum of squares (wave scan, in regs) ------------
    float p0 = q.x * q.x;
    float p1 = p0 + q.y * q.y;
    float p2 = p1 + q.z * q.z;
    float p3 = p2 + q.w * q.w;
    float sc = p3;
#pragma unroll
    for (int off = 1; off < 64; off <<= 1) {
        float o = __shfl_up(sc, off);
        if (lane >= off) sc += o;
    }
    float base = sc - p3;
    float4 csv;
    csv.x = base + p0; csv.y = base + p1; csv.z = base + p2; csv.w = base + p3;
    float s256 = R[slotE(256)];               // broadcast (same-wave write visible)
    float totE = __shfl(sc, 63) + s256 * s256;

    // ---------------- phase 3: autocorrelation, K-split 4 x 16-tau blocking ------
    // lane = (g,i): g = lane>>4 covers j in [64g,64g+64); i = lane&15 covers taus
    // 16i..16i+15. Named-scalar 20-float window, shift-by-4 per step (SSA renames,
    // zero cost). A_k += c_m * w_{m+k}; same relative pattern every step.
    const int g  = lane >> 4;
    const int ii = lane & 15;
    const int Ebase = (g << 6) + (ii << 4);   // 64g + 16i

    float A0 = 0.f, A1 = 0.f, A2 = 0.f, A3 = 0.f, A4 = 0.f, A5 = 0.f, A6 = 0.f, A7 = 0.f;
    float A8 = 0.f, A9 = 0.f, A10 = 0.f, A11 = 0.f, A12 = 0.f, A13 = 0.f, A14 = 0.f, A15 = 0.f;

#define LD4(X) (*(const float4*)(R + slotE(X)))

    float w0, w1, w2, w3, w4, w5, w6, w7, w8, w9;
    float w10, w11, w12, w13, w14, w15, w16, w17, w18, w19;
    {
        float4 t;
        t = LD4(Ebase + 0);  w0  = t.x; w1  = t.y; w2  = t.z; w3  = t.w;
        t = LD4(Ebase + 4);  w4  = t.x; w5  = t.y; w6  = t.z; w7  = t.w;
        t = LD4(Ebase + 8);  w8  = t.x; w9  = t.y; w10 = t.z; w11 = t.w;
        t = LD4(Ebase + 12); w12 = t.x; w13 = t.y; w14 = t.z; w15 = t.w;
        t = LD4(Ebase + 16); w16 = t.x; w17 = t.y; w18 = t.z; w19 = t.w;
    }
    float4 cq = LD4(g << 6);

#define FMA4(K, WA, WB, WC, WD)                                                  \
    A##K = fmaf(c0, WA, A##K); A##K = fmaf(c1, WB, A##K);                        \
    A##K = fmaf(c2, WC, A##K); A##K = fmaf(c3, WD, A##K);

#define DO_FMAS                                                                  \
    FMA4(0,  w0,  w1,  w2,  w3)   FMA4(1,  w1,  w2,  w3,  w4)                    \
    FMA4(2,  w2,  w3,  w4,  w5)   FMA4(3,  w3,  w4,  w5,  w6)                    \
    FMA4(4,  w4,  w5,  w6,  w7)   FMA4(5,  w5,  w6,  w7,  w8)                    \
    FMA4(6,  w6,  w7,  w8,  w9)   FMA4(7,  w7,  w8,  w9,  w10)                   \
    FMA4(8,  w8,  w9,  w10, w11)  FMA4(9,  w9,  w10, w11, w12)                   \
    FMA4(10, w10, w11, w12, w13)  FMA4(11, w11, w12, w13, w14)                   \
    FMA4(12, w12, w13, w14, w15)  FMA4(13, w13, w14, w15, w16)                   \
    FMA4(14, w14, w15, w16, w17)  FMA4(15, w15, w16, w17, w18)

#define SHIFT16                                                                  \
    w0 = w4;  w1 = w5;  w2 = w6;  w3 = w7;  w4 = w8;  w5 = w9;                   \
    w6 = w10; w7 = w11; w8 = w12; w9 = w13; w10 = w14; w11 = w15;                \
    w12 = w16; w13 = w17; w14 = w18; w15 = w19;

#define DO_STEP(T)                                                               \
    {                                                                            \
        const float c0 = cq.x, c1 = cq.y, c2 = cq.z, c3 = cq.w;                  \
        float4 nw, nc;                                                           \
        if ((T) < 15) {                                                          \
            nw = LD4(Ebase + 4 * (T) + 20);                                      \
            nc = LD4((g << 6) + 4 * (T) + 4);                                    \
        }                                                                        \
        DO_FMAS                                                                  \
        if ((T) < 15) {                                                          \
            SHIFT16                                                              \
            w16 = nw.x; w17 = nw.y; w18 = nw.z; w19 = nw.w;                      \
            cq = nc;                                                             \
        }                                                                        \
    }

    DO_STEP(0)  DO_STEP(1)  DO_STEP(2)  DO_STEP(3)
    DO_STEP(4)  DO_STEP(5)  DO_STEP(6)  DO_STEP(7)
    DO_STEP(8)  DO_STEP(9)  DO_STEP(10) DO_STEP(11)
    DO_STEP(12) DO_STEP(13) DO_STEP(14) DO_STEP(15)
#undef DO_STEP
#undef SHIFT16
#undef DO_FMAS
#undef FMA4

    // ---------------- phase 4: reduce partials over g (LDS round-trip) -----------
    // part[g][tau], chunk index = 66g + 4i + q. Aliases the s region (s is dead).
    {
        float4 v4;
        v4.x = A0;  v4.y = A1;  v4.z = A2;  v4.w = A3;
        *(float4*)(R + slotC(g * 66 + ii * 4 + 0)) = v4;
        v4.x = A4;  v4.y = A5;  v4.z = A6;  v4.w = A7;
        *(float4*)(R + slotC(g * 66 + ii * 4 + 1)) = v4;
        v4.x = A8;  v4.y = A9;  v4.z = A10; v4.w = A11;
        *(float4*)(R + slotC(g * 66 + ii * 4 + 2)) = v4;
        v4.x = A12; v4.y = A13; v4.z = A14; v4.w = A15;
        *(float4*)(R + slotC(g * 66 + ii * 4 + 3)) = v4;
    }
    float a0, a1, a2, a3;
    {
        float4 u0 = *(const float4*)(R + slotC(0 * 66 + lane));
        float4 u1 = *(const float4*)(R + slotC(1 * 66 + lane));
        float4 u2 = *(const float4*)(R + slotC(2 * 66 + lane));
        float4 u3 = *(const float4*)(R + slotC(3 * 66 + lane));
        a0 = (u0.x + u1.x) + (u2.x + u3.x);
        a1 = (u0.y + u1.y) + (u2.y + u3.y);
        a2 = (u0.z + u1.z) + (u2.z + u3.z);
        a3 = (u0.w + u1.w) + (u2.w + u3.w);
    }
    // lane now owns corr[4l..4l+3]

    // ---------------- phase 5: CMND (4-tau/lane layout) --------------------------
    *(float4*)(R + slotE(4 * lane)) = csv;    // cs[e], aliases part (dead)
    if (lane == 0) R[slotE(256)] = totE;
    float4 csr  = *(const float4*)(R + slotE(252 - 4 * lane));
    float csTop = R[slotE(256 - 4 * lane)];

    float d0 = csTop - 2.0f * a0 + totE - csv.x;
    float d1 = csr.w - 2.0f * a1 + totE - csv.y;
    float d2 = csr.z - 2.0f * a2 + totE - csv.z;
    float d3 = csr.y - 2.0f * a3 + totE - csv.w;
    if (lane == 0) d0 = 0.0f;                 // diff[0] excluded from prefix
    float l0 = d0, l1 = l0 + d1, l2 = l1 + d2, l3 = l2 + d3;
    float scn = l3;
#pragma unroll
    for (int off = 1; off < 64; off <<= 1) {
        float o = __shfl_up(scn, off);
        if (lane >= off) scn += o;
    }
    float pb = scn - l3;
    const int t0 = 4 * lane;
    float cd0 = d0 * (float)(t0 + 0) / (pb + l0 + 1e-7f);
    float cd1 = d1 * (float)(t0 + 1) / (pb + l1 + 1e-7f);
    float cd2 = d2 * (float)(t0 + 2) / (pb + l2 + 1e-7f);
    float cd3 = d3 * (float)(t0 + 3) / (pb + l3 + 1e-7f);
    if (lane <= 53) {                          // taus 0..215 (>=213 junk, never read)
        float4 cdv;
        cdv.x = (lane == 0) ? 1.0f : cd0;
        cdv.y = cd1; cdv.z = cd2; cdv.w = cd3;
        *(float4*)(R + slotE(CM_BASE + t0)) = cdv;
    }

    // ---------------- phase 6: threshold + tau searches via ballot ---------------
    // cmnd[i] = R[CM_BASE + 26 + i], i in [0,187). Named scalars only.
    const float am0  = R[slotE(CM_BASE + 25 + lane)];
    const float bm0  = R[slotE(CM_BASE + 26 + lane)];
    const float cn0  = R[slotE(CM_BASE + 27 + lane)];
    const float am1  = R[slotE(CM_BASE + 25 + 64 + lane)];
    const float bm1  = R[slotE(CM_BASE + 26 + 64 + lane)];
    const float cn1  = R[slotE(CM_BASE + 27 + 64 + lane)];
    const float am2  = R[slotE(CM_BASE + 25 + 128 + lane)];
    const float bm2  = R[slotE(CM_BASE + 26 + 128 + lane)];
    const float cn2  = R[slotE(CM_BASE + 27 + 128 + lane)];

    unsigned long long tm0 = __ballot((lane < 187)       && (bm0 < 0.1f));
    unsigned long long tm1 = __ballot((64 + lane < 187)  && (bm1 < 0.1f));
    unsigned long long tm2 = __ballot((128 + lane < 187) && (bm2 < 0.1f));
    int cand = tm0 ? (__ffsll(tm0) - 1)
             : (tm1 ? (64 + __ffsll(tm1) - 1)
             : (tm2 ? (128 + __ffsll(tm2) - 1) : 999));
    const int thold = (cand == 0 || cand == 999) ? C_LEN : cand;

    const int i0 = lane, i1 = 64 + lane, i2 = 128 + lane;
    bool L0 = (i0 == 0)   || (bm0 - am0 <= 0.0f);
    bool R0 = (i0 == 186) || (cn0 - bm0 >= 0.0f);
    bool L1 = (bm1 - am1 <= 0.0f);
    bool R1 = (cn1 - bm1 >= 0.0f);
    bool L2 = (bm2 - am2 <= 0.0f);
    bool R2 = (i2 == 186) || (cn2 - bm2 >= 0.0f);
    unsigned long long lm0 = __ballot((i0 >= thold) && (i0 < C_LEN) && L0 && R0);
    unsigned long long lm1 = __ballot((i1 >= thold) && (i1 < C_LEN) && L1 && R1);
    unsigned long long lm2 = __ballot((i2 >= thold) && (i2 < C_LEN) && L2 && R2);
    int tcand = lm0 ? (__ffsll(lm0) - 1)
              : (lm1 ? (64 + __ffsll(lm1) - 1)
              : (lm2 ? (128 + __ffsll(lm2) - 1) : 999));
    const int tau = (tcand == 999) ? 0 : tcand;

    // ---------------- phase 7: parabolic interp + pitch --------------------------
    float pv = 0.0f;
    if (tau > 0) {
        float shift = 0.0f;
        if (tau <= C_LEN - 2) {
            float pp = R[slotE(CM_BASE + 26 + tau - 1)];
            float cc = R[slotE(CM_BASE + 26 + tau)];
            float nn = R[slotE(CM_BASE + 26 + tau + 1)];
            float aa = nn + pp - 2.0f * cc;
            float bb = 0.5f * (nn - pp);
            shift = (fabsf(bb) >= fabsf(aa)) ? 0.0f : (-bb / aa);
        }
        pv = 16000.0f / ((float)(tau + TAU_MINC + 1) + shift);
    }
    if (lane == 0) pitch[frame] = pv;
}

// 30-wide median (index 14 of ascending sort), edge-padded (15,14).
// Fully unrolled selection so v[] stays in registers (no runtime indexing).
__global__ __launch_bounds__(256) void median_k(const float* __restrict__ pitch,
                                                float* __restrict__ out) {
    int idx = blockIdx.x * blockDim.x + threadIdx.x;
    if (idx >= NFRAMES) return;
    int b = idx / NF;
    int f = idx - b * NF;
    const float* p = pitch + b * NF;
    float v[30];
#pragma unroll
    for (int k = 0; k < 30; ++k) {
        int j = f + k - 15;
        j = (j < 0) ? 0 : ((j > NF - 1) ? NF - 1 : j);
        v[k] = p[j];
    }
    float result = 0.0f;
#pragma unroll
    for (int i = 0; i < 30; ++i) {
        int lt = 0, le = 0;
#pragma unroll
        for (int j = 0; j < 30; ++j) {
            lt += (v[j] < v[i]);
            le += (v[j] <= v[i]);
        }
        if (lt <= 14 && 14 < le) result = v[i];
    }
    out[idx] = result;
}

extern "C" void kernel_launch(void* const* d_in, const int* in_sizes, int n_in,
                              void* d_out, int out_size, void* d_ws, size_t ws_size,
                              hipStream_t stream) {
    (void)in_sizes; (void)n_in; (void)out_size; (void)ws_size;
    const float* in = (const float*)d_in[0];
    float* out = (float*)d_out;
    float* pitch = (float*)d_ws;     // NFRAMES floats = 256 KB scratch

    yin_frames<<<NFRAMES / 4, 256, 0, stream>>>(in, pitch);
    median_k<<<(NFRAMES + 255) / 256, 256, 0, stream>>>(pitch, out);
}

// Round 6
// 132.743 us; speedup vs baseline: 9.6944x; 1.1998x over previous
//
#include <hip/hip_runtime.h>
#include <math.h>

// YIN pitch, MI355X. Constants from reference:
//   SR=16000, STRIDES=160, W=257, TAU_MAX=213, TAU_MIN=26, C=187, MEDIAN=30
#define T_LEN    160000
#define STRIDES  160
#define NF       1001
#define NB       64
#define W_LEN    257
#define TAU_MINC 26
#define C_LEN    187
#define NFRAMES  (NB * NF)     // 64064

// Per-wave LDS map (floats). Signal uses the chunk-padded slotE layout
// (slot(C)=C+(C>>3)) so the stride-16-element window reads spread across
// bank-quads. part aliases the (dead) signal region with a hand-designed
// conflict-free stride layout. cs/cm live in dedicated space above.
#define RF     1664            // 416 chunks
#define CS_F   1160            // cumsum-of-squares array, 257 floats
#define CM_F   1424            // cmnd array, 216 floats used
#define PCHUNK(g, q, ii) ((g) * 73 + (q) * 18 + (ii))   // max 288 < 290

__device__ __forceinline__ int slotE(int E) {   // padded float index
    int C = E >> 2;
    return ((C + (C >> 3)) << 2) | (E & 3);
}

// R2-R4 lesson: float arrays with ANY runtime-looking index survive SROA as
// allocas -> scratch -> 6 GB HBM traffic. Hot loop uses ONLY named scalars.

__global__ __launch_bounds__(64, 5) void yin_frames(const float* __restrict__ in,
                                                    float* __restrict__ pitch) {
    __shared__ float R[RF];

    const int lane  = threadIdx.x;            // 64-thread block = 1 wave
    const int frame = blockIdx.x;
    const int b = frame / NF;
    const int f = frame - b * NF;

    // ---------------- phase 1: zero pad region + stage frame ---------------------
    // zero raw floats [288, 580): padded slots of elements 256..515
    float4 z4; z4.x = 0.f; z4.y = 0.f; z4.z = 0.f; z4.w = 0.f;
    *(float4*)(R + 288 + 4 * lane) = z4;
    if (lane < 9) *(float4*)(R + 544 + 4 * lane) = z4;

    const float* src = in + (size_t)b * T_LEN;
    const int start = f * STRIDES;
    int e0 = start + 4 * lane;
    float4 q;
    if (e0 + 3 < T_LEN) {
        q = *(const float4*)(src + e0);
    } else {
        q.x = (e0 + 0 < T_LEN) ? src[e0 + 0] : 0.f;
        q.y = (e0 + 1 < T_LEN) ? src[e0 + 1] : 0.f;
        q.z = (e0 + 2 < T_LEN) ? src[e0 + 2] : 0.f;
        q.w = (e0 + 3 < T_LEN) ? src[e0 + 3] : 0.f;
    }
    *(float4*)(R + slotE(4 * lane)) = q;      // elements 4l..4l+3 (slots <= 283)
    if (lane == 0) {
        int e2 = start + 256;
        R[slotE(256)] = (e2 < T_LEN) ? src[e2] : 0.f;   // slot 288 (after zeroing)
    }

    // ---------------- phase 2: cumsum of squares (wave scan) ---------------------
    float p0 = q.x * q.x;
    float p1 = p0 + q.y * q.y;
    float p2 = p1 + q.z * q.z;
    float p3 = p2 + q.w * q.w;
    float sc = p3;
#pragma unroll
    for (int off = 1; off < 64; off <<= 1) {
        float o = __shfl_up(sc, off);
        if (lane >= off) sc += o;
    }
    {
        float base = sc - p3;
        float4 csv;
        csv.x = base + p0; csv.y = base + p1; csv.z = base + p2; csv.w = base + p3;
        *(float4*)(R + CS_F + 4 * lane) = csv;   // park cs[] in LDS now: frees regs
    }
    float s256 = R[slotE(256)];
    float totE = __shfl(sc, 63) + s256 * s256;
    if (lane == 63) R[CS_F + 256] = totE;

    // ---------------- phase 3: autocorrelation, K-split 4 x 16-tau blocking ------
    // lane = (g,ii): g = lane>>4 covers j in [64g,64g+64); ii = lane&15 covers
    // taus 16ii..16ii+15. Named-scalar 20-float window, shift-by-4 per step.
    const int g  = lane >> 4;
    const int ii = lane & 15;
    const int Ebase = (g << 6) + (ii << 4);   // 64g + 16ii

    float A0 = 0.f, A1 = 0.f, A2 = 0.f, A3 = 0.f, A4 = 0.f, A5 = 0.f, A6 = 0.f, A7 = 0.f;
    float A8 = 0.f, A9 = 0.f, A10 = 0.f, A11 = 0.f, A12 = 0.f, A13 = 0.f, A14 = 0.f, A15 = 0.f;

#define LD4(X) (*(const float4*)(R + slotE(X)))

    float w0, w1, w2, w3, w4, w5, w6, w7, w8, w9;
    float w10, w11, w12, w13, w14, w15, w16, w17, w18, w19;
    {
        float4 t;
        t = LD4(Ebase + 0);  w0  = t.x; w1  = t.y; w2  = t.z; w3  = t.w;
        t = LD4(Ebase + 4);  w4  = t.x; w5  = t.y; w6  = t.z; w7  = t.w;
        t = LD4(Ebase + 8);  w8  = t.x; w9  = t.y; w10 = t.z; w11 = t.w;
        t = LD4(Ebase + 12); w12 = t.x; w13 = t.y; w14 = t.z; w15 = t.w;
        t = LD4(Ebase + 16); w16 = t.x; w17 = t.y; w18 = t.z; w19 = t.w;
    }
    float4 cq = LD4(g << 6);

#define FMA4(K, WA, WB, WC, WD)                                                  \
    A##K = fmaf(c0, WA, A##K); A##K = fmaf(c1, WB, A##K);                        \
    A##K = fmaf(c2, WC, A##K); A##K = fmaf(c3, WD, A##K);

#define DO_FMAS                                                                  \
    FMA4(0,  w0,  w1,  w2,  w3)   FMA4(1,  w1,  w2,  w3,  w4)                    \
    FMA4(2,  w2,  w3,  w4,  w5)   FMA4(3,  w3,  w4,  w5,  w6)                    \
    FMA4(4,  w4,  w5,  w6,  w7)   FMA4(5,  w5,  w6,  w7,  w8)                    \
    FMA4(6,  w6,  w7,  w8,  w9)   FMA4(7,  w7,  w8,  w9,  w10)                   \
    FMA4(8,  w8,  w9,  w10, w11)  FMA4(9,  w9,  w10, w11, w12)                   \
    FMA4(10, w10, w11, w12, w13)  FMA4(11, w11, w12, w13, w14)                   \
    FMA4(12, w12, w13, w14, w15)  FMA4(13, w13, w14, w15, w16)                   \
    FMA4(14, w14, w15, w16, w17)  FMA4(15, w15, w16, w17, w18)

#define SHIFT16                                                                  \
    w0 = w4;  w1 = w5;  w2 = w6;  w3 = w7;  w4 = w8;  w5 = w9;                   \
    w6 = w10; w7 = w11; w8 = w12; w9 = w13; w10 = w14; w11 = w15;                \
    w12 = w16; w13 = w17; w14 = w18; w15 = w19;

#define DO_STEP(T)                                                               \
    {                                                                            \
        const float c0 = cq.x, c1 = cq.y, c2 = cq.z, c3 = cq.w;                  \
        float4 nw, nc;                                                           \
        if ((T) < 15) {                                                          \
            nw = LD4(Ebase + 4 * (T) + 20);                                      \
            nc = LD4((g << 6) + 4 * (T) + 4);                                    \
        }                                                                        \
        DO_FMAS                                                                  \
        if ((T) < 15) {                                                          \
            SHIFT16                                                              \
            w16 = nw.x; w17 = nw.y; w18 = nw.z; w19 = nw.w;                      \
            cq = nc;                                                             \
        }                                                                        \
    }

    DO_STEP(0)  DO_STEP(1)  DO_STEP(2)  DO_STEP(3)
    DO_STEP(4)  DO_STEP(5)  DO_STEP(6)  DO_STEP(7)
    DO_STEP(8)  DO_STEP(9)  DO_STEP(10) DO_STEP(11)
    DO_STEP(12) DO_STEP(13) DO_STEP(14) DO_STEP(15)
#undef DO_STEP
#undef SHIFT16
#undef DO_FMAS
#undef FMA4

    // ---------------- phase 4: reduce partials over g ----------------------------
    // part quad (g,ii,q) holds taus 16ii+4q..+3 partial-g, at chunk 73g+18q+ii.
    // Writes: stride-1 in ii within each 16-lane group -> conflict-free.
    // Reads: {18q+ii mod 8} covers each bank-quad exactly 2x -> conflict-free.
    // Aliases the signal region (floats <= 1143 < CS_F) - signal is dead now.
    {
        float4 v4;
        v4.x = A0;  v4.y = A1;  v4.z = A2;  v4.w = A3;
        *(float4*)(R + 4 * PCHUNK(g, 0, ii)) = v4;
        v4.x = A4;  v4.y = A5;  v4.z = A6;  v4.w = A7;
        *(float4*)(R + 4 * PCHUNK(g, 1, ii)) = v4;
        v4.x = A8;  v4.y = A9;  v4.z = A10; v4.w = A11;
        *(float4*)(R + 4 * PCHUNK(g, 2, ii)) = v4;
        v4.x = A12; v4.y = A13; v4.z = A14; v4.w = A15;
        *(float4*)(R + 4 * PCHUNK(g, 3, ii)) = v4;
    }
    float a0, a1, a2, a3;
    {
        const int iio = lane >> 2, qo = lane & 3;
        float4 u0 = *(const float4*)(R + 4 * PCHUNK(0, qo, iio));
        float4 u1 = *(const float4*)(R + 4 * PCHUNK(1, qo, iio));
        float4 u2 = *(const float4*)(R + 4 * PCHUNK(2, qo, iio));
        float4 u3 = *(const float4*)(R + 4 * PCHUNK(3, qo, iio));
        a0 = (u0.x + u1.x) + (u2.x + u3.x);
        a1 = (u0.y + u1.y) + (u2.y + u3.y);
        a2 = (u0.z + u1.z) + (u2.z + u3.z);
        a3 = (u0.w + u1.w) + (u2.w + u3.w);
    }
    // lane now owns corr[4l..4l+3]

    // ---------------- phase 5: CMND --------------------------------------------
    float4 csv  = *(const float4*)(R + CS_F + 4 * lane);
    float4 csr  = *(const float4*)(R + CS_F + 252 - 4 * lane);
    float csTop = R[CS_F + 256 - 4 * lane];

    float d0 = csTop - 2.0f * a0 + totE - csv.x;
    float d1 = csr.w - 2.0f * a1 + totE - csv.y;
    float d2 = csr.z - 2.0f * a2 + totE - csv.z;
    float d3 = csr.y - 2.0f * a3 + totE - csv.w;
    if (lane == 0) d0 = 0.0f;                 // diff[0] excluded from prefix
    float l0 = d0, l1 = l0 + d1, l2 = l1 + d2, l3 = l2 + d3;
    float scn = l3;
#pragma unroll
    for (int off = 1; off < 64; off <<= 1) {
        float o = __shfl_up(scn, off);
        if (lane >= off) scn += o;
    }
    float pb = scn - l3;
    const int t0 = 4 * lane;
    float cd0 = d0 * (float)(t0 + 0) / (pb + l0 + 1e-7f);
    float cd1 = d1 * (float)(t0 + 1) / (pb + l1 + 1e-7f);
    float cd2 = d2 * (float)(t0 + 2) / (pb + l2 + 1e-7f);
    float cd3 = d3 * (float)(t0 + 3) / (pb + l3 + 1e-7f);
    if (lane <= 53) {                          // taus 0..215 (>=213 junk, never used)
        float4 cdv;
        cdv.x = (lane == 0) ? 1.0f : cd0;
        cdv.y = cd1; cdv.z = cd2; cdv.w = cd3;
        *(float4*)(R + CM_F + t0) = cdv;
    }

    // ---------------- phase 6: threshold + tau searches via ballot ---------------
    // cmnd[i] = R[CM_F + 26 + i], i in [0,187). Named scalars only.
    const float am0  = R[CM_F + 25 + lane];
    const float bm0  = R[CM_F + 26 + lane];
    const float cn0  = R[CM_F + 27 + lane];
    const float am1  = R[CM_F + 25 + 64 + lane];
    const float bm1  = R[CM_F + 26 + 64 + lane];
    const float cn1  = R[CM_F + 27 + 64 + lane];
    const float am2  = R[CM_F + 25 + 128 + lane];
    const float bm2  = R[CM_F + 26 + 128 + lane];
    const float cn2  = R[CM_F + 27 + 128 + lane];   // <=1642 < RF, junk masked

    unsigned long long tm0 = __ballot((lane < 187)       && (bm0 < 0.1f));
    unsigned long long tm1 = __ballot((64 + lane < 187)  && (bm1 < 0.1f));
    unsigned long long tm2 = __ballot((128 + lane < 187) && (bm2 < 0.1f));
    int cand = tm0 ? (__ffsll(tm0) - 1)
             : (tm1 ? (64 + __ffsll(tm1) - 1)
             : (tm2 ? (128 + __ffsll(tm2) - 1) : 999));
    const int thold = (cand == 0 || cand == 999) ? C_LEN : cand;

    const int i0 = lane, i1 = 64 + lane, i2 = 128 + lane;
    bool L0 = (i0 == 0)   || (bm0 - am0 <= 0.0f);
    bool R0 = (i0 == 186) || (cn0 - bm0 >= 0.0f);
    bool L1 = (bm1 - am1 <= 0.0f);
    bool R1 = (cn1 - bm1 >= 0.0f);
    bool L2 = (bm2 - am2 <= 0.0f);
    bool R2 = (i2 == 186) || (cn2 - bm2 >= 0.0f);
    unsigned long long lm0 = __ballot((i0 >= thold) && (i0 < C_LEN) && L0 && R0);
    unsigned long long lm1 = __ballot((i1 >= thold) && (i1 < C_LEN) && L1 && R1);
    unsigned long long lm2 = __ballot((i2 >= thold) && (i2 < C_LEN) && L2 && R2);
    int tcand = lm0 ? (__ffsll(lm0) - 1)
              : (lm1 ? (64 + __ffsll(lm1) - 1)
              : (lm2 ? (128 + __ffsll(lm2) - 1) : 999));
    const int tau = (tcand == 999) ? 0 : tcand;

    // ---------------- phase 7: parabolic interp + pitch --------------------------
    float pv = 0.0f;
    if (tau > 0) {
        float shift = 0.0f;
        if (tau <= C_LEN - 2) {
            float pp = R[CM_F + 26 + tau - 1];
            float cc = R[CM_F + 26 + tau];
            float nn = R[CM_F + 26 + tau + 1];
            float aa = nn + pp - 2.0f * cc;
            float bb = 0.5f * (nn - pp);
            shift = (fabsf(bb) >= fabsf(aa)) ? 0.0f : (-bb / aa);
        }
        pv = 16000.0f / ((float)(tau + TAU_MINC + 1) + shift);
    }
    if (lane == 0) pitch[frame] = pv;
}

// 30-wide median (index 14 of ascending sort), edge-padded (15,14).
// Fully unrolled selection so v[] stays in registers.
__global__ __launch_bounds__(256) void median_k(const float* __restrict__ pitch,
                                                float* __restrict__ out) {
    int idx = blockIdx.x * blockDim.x + threadIdx.x;
    if (idx >= NFRAMES) return;
    int b = idx / NF;
    int f = idx - b * NF;
    const float* p = pitch + b * NF;
    float v[30];
#pragma unroll
    for (int k = 0; k < 30; ++k) {
        int j = f + k - 15;
        j = (j < 0) ? 0 : ((j > NF - 1) ? NF - 1 : j);
        v[k] = p[j];
    }
    float result = 0.0f;
#pragma unroll
    for (int i = 0; i < 30; ++i) {
        int lt = 0, le = 0;
#pragma unroll
        for (int j = 0; j < 30; ++j) {
            lt += (v[j] < v[i]);
            le += (v[j] <= v[i]);
        }
        if (lt <= 14 && 14 < le) result = v[i];
    }
    out[idx] = result;
}

extern "C" void kernel_launch(void* const* d_in, const int* in_sizes, int n_in,
                              void* d_out, int out_size, void* d_ws, size_t ws_size,
                              hipStream_t stream) {
    (void)in_sizes; (void)n_in; (void)out_size; (void)ws_size;
    const float* in = (const float*)d_in[0];
    float* out = (float*)d_out;
    float* pitch = (float*)d_ws;     // NFRAMES floats = 256 KB scratch

    yin_frames<<<NFRAMES, 64, 0, stream>>>(in, pitch);
    median_k<<<(NFRAMES + 255) / 256, 256, 0, stream>>>(pitch, out);
}

// Round 8
// 111.716 us; speedup vs baseline: 11.5190x; 1.1882x over previous
//
#include <hip/hip_runtime.h>
#include <math.h>

// YIN pitch, MI355X. Constants from reference:
//   SR=16000, STRIDES=160, W=257, TAU_MAX=213, TAU_MIN=26, C=187, MEDIAN=30
#define T_LEN    160000
#define STRIDES  160
#define NF       1001
#define NB       64
#define TAU_MINC 26
#define C_LEN    187
#define NFRAMES  (NB * NF)     // 64064

// Per-wave LDS map (floats). Regions (sequential lifetimes, wave-synchronous):
//   [0,292)      SH: f16 signal, 292 padded u32 (584 halfs). Dead after phase 3.
//   [292,1452)   part: phase-4 partials (289 chunks). Written after SH dead.
//                CM aliases [292,512) in phase 5 (after part reads done).
//   [1452,1712)  CS: cumsum of squares, 257 floats.
#define WAVE_F  1712
#define PB      292
#define CS_B    1452
#define CM_B    292
#define PCHUNK(g, q, ii) ((g) * 73 + (q) * 18 + (ii))   // chunk idx, max 288

// Padded u32 index for the f16 signal: insert one 16B chunk every 8 chunks so
// the 16 ii-lanes' window reads (u32 stride 8) spread 2-per-bank-quad.
#define SLOTU(U) ((U) + 4 * ((U) >> 5))

// clang's AMDGPU builtins use __fp16 vectors ('h' in builtin signatures):
//   __builtin_amdgcn_cvt_pkrtz : (float,float) -> V2h
//   __builtin_amdgcn_fdot2     : (V2h, V2h, float, bool) -> float
typedef __fp16 half2_t __attribute__((ext_vector_type(2)));
union H2U { half2_t h; unsigned int u; };

__device__ __forceinline__ unsigned int pack2h(float a, float b) {
    H2U x;
#if __has_builtin(__builtin_amdgcn_cvt_pkrtz)
    x.h = __builtin_amdgcn_cvt_pkrtz(a, b);
#else
    x.h.x = (__fp16)a; x.h.y = (__fp16)b;
#endif
    return x.u;
}

__device__ __forceinline__ float fdot2f(unsigned int a, unsigned int b, float c) {
    H2U ua, ub; ua.u = a; ub.u = b;
#if __has_builtin(__builtin_amdgcn_fdot2)
    return __builtin_amdgcn_fdot2(ua.h, ub.h, c, false);
#else
    return c + (float)ua.h.x * (float)ub.h.x + (float)ua.h.y * (float)ub.h.y;
#endif
}

// odd-pair from two aligned pairs: (halfs 2i+1, 2i+2)
#define AB(HI, LO) ((unsigned int)(((LO) >> 16) | ((HI) << 16)))

// R2-R4 lesson: arrays with computed indices survive SROA as allocas ->
// scratch -> 6 GB HBM. Hot loop uses ONLY named scalars (proven R5/R6).

__global__ __launch_bounds__(128, 5) void yin_frames(const float* __restrict__ in,
                                                     float* __restrict__ pitch) {
    __shared__ __align__(16) float SB_[2][WAVE_F];

    const int wid  = threadIdx.x >> 6;
    const int lane = threadIdx.x & 63;
    const int frame = blockIdx.x * 2 + wid;
    const int b = frame / NF;
    const int f = frame - b * NF;
    float* SB = SB_[wid];
    unsigned int* SHu = (unsigned int*)SB;

    // ---------------- phase 1: zero padded f16 region + stage frame --------------
    {
        uint4 z; z.x = 0u; z.y = 0u; z.z = 0u; z.w = 0u;
        *(uint4*)(SHu + 4 * lane) = z;                 // u32 [0,256)
        if (lane < 9) *(uint4*)(SHu + 256 + 4 * lane) = z;  // u32 [256,292)
    }
    const float* src = in + (size_t)b * T_LEN;
    const int start = f * STRIDES;
    int e0 = start + 4 * lane;
    float4 q;
    if (e0 + 3 < T_LEN) {
        q = *(const float4*)(src + e0);
    } else {
        q.x = (e0 + 0 < T_LEN) ? src[e0 + 0] : 0.f;
        q.y = (e0 + 1 < T_LEN) ? src[e0 + 1] : 0.f;
        q.z = (e0 + 2 < T_LEN) ? src[e0 + 2] : 0.f;
        q.w = (e0 + 3 < T_LEN) ? src[e0 + 3] : 0.f;
    }
    {   // halfs 4l..4l+3 at padded u32 2l(+pad); pair doesn't cross a pad chunk
        uint2 d; d.x = pack2h(q.x, q.y); d.y = pack2h(q.z, q.w);
        *(uint2*)(SHu + 2 * lane + 4 * (lane >> 4)) = d;
    }
    float s256f = 0.0f;
    if (lane == 0) {
        int e2 = start + 256;
        s256f = (e2 < T_LEN) ? src[e2] : 0.f;
        SHu[SLOTU(128)] = pack2h(s256f, 0.f);          // halfs 256,257
    }
    s256f = __shfl(s256f, 0);

    // ---------------- phase 2: cumsum of squares (fp32, wave scan) ---------------
    float p0 = q.x * q.x;
    float p1 = p0 + q.y * q.y;
    float p2 = p1 + q.z * q.z;
    float p3 = p2 + q.w * q.w;
    float sc = p3;
#pragma unroll
    for (int off = 1; off < 64; off <<= 1) {
        float o = __shfl_up(sc, off);
        if (lane >= off) sc += o;
    }
    {
        float base = sc - p3;
        float4 csv;
        csv.x = base + p0; csv.y = base + p1; csv.z = base + p2; csv.w = base + p3;
        *(float4*)(SB + CS_B + 4 * lane) = csv;        // park cs[] in LDS
    }
    float totE = __shfl(sc, 63) + s256f * s256f;
    if (lane == 63) SB[CS_B + 256] = totE;

    // ---------------- phase 3: autocorr via v_dot2_f32_f16 -----------------------
    // lane = (g,ii): g covers j in [64g,64g+64), ii covers taus 16ii..16ii+15.
    // Window: aligned-pair u32 file aw[n mod 20] (absolute u32 n = 32g+8ii+n'),
    // odd-pair file ow[n mod 20] = AB(aw[n+1], aw[n]). Per 8-j block: 64 dot2.
    const int g  = lane >> 4;
    const int ii = lane & 15;
    const int W0u = 32 * g + 8 * ii;                   // unpadded u32 window base

    float A0 = 0.f, A1 = 0.f, A2 = 0.f, A3 = 0.f, A4 = 0.f, A5 = 0.f, A6 = 0.f, A7 = 0.f;
    float A8 = 0.f, A9 = 0.f, A10 = 0.f, A11 = 0.f, A12 = 0.f, A13 = 0.f, A14 = 0.f, A15 = 0.f;

    unsigned int aw0, aw1, aw2, aw3, aw4, aw5, aw6, aw7, aw8, aw9;
    unsigned int aw10, aw11, aw12, aw13, aw14, aw15, aw16, aw17, aw18, aw19;
    unsigned int ow0 = 0, ow1 = 0, ow2 = 0, ow3 = 0, ow4 = 0, ow5 = 0, ow6 = 0, ow7 = 0;
    unsigned int ow8 = 0, ow9 = 0, ow10 = 0, ow11 = 0, ow12 = 0, ow13 = 0, ow14 = 0;
    unsigned int ow15 = 0, ow16 = 0, ow17 = 0, ow18 = 0, ow19 = 0;
    (void)ow15; (void)ow16; (void)ow17; (void)ow18; (void)ow19;

    {
        uint4 t;
        t = *(const uint4*)(SHu + SLOTU(W0u + 0));  aw0 = t.x; aw1 = t.y; aw2 = t.z; aw3 = t.w;
        t = *(const uint4*)(SHu + SLOTU(W0u + 4));  aw4 = t.x; aw5 = t.y; aw6 = t.z; aw7 = t.w;
        t = *(const uint4*)(SHu + SLOTU(W0u + 8));  aw8 = t.x; aw9 = t.y; aw10 = t.z; aw11 = t.w;
        t = *(const uint4*)(SHu + SLOTU(W0u + 12)); aw12 = t.x; aw13 = t.y; aw14 = t.z; aw15 = t.w;
    }
    ow0 = AB(aw1, aw0);  ow1 = AB(aw2, aw1);  ow2 = AB(aw3, aw2);  ow3 = AB(aw4, aw3);
    ow4 = AB(aw5, aw4);  ow5 = AB(aw6, aw5);  ow6 = AB(aw7, aw6);  ow7 = AB(aw8, aw7);
    ow8 = AB(aw9, aw8);  ow9 = AB(aw10, aw9); ow10 = AB(aw11, aw10);

// even tau 2e uses aligned pair x(p+e); odd tau 2e+1 uses odd pair y(p+e)
#define PSTEP(CP, e0_, e1_, e2_, e3_, e4_, e5_, e6_, e7_, o0_, o1_, o2_, o3_, o4_, o5_, o6_, o7_) \
    A0  = fdot2f(CP, e0_, A0);  A1  = fdot2f(CP, o0_, A1);                        \
    A2  = fdot2f(CP, e1_, A2);  A3  = fdot2f(CP, o1_, A3);                        \
    A4  = fdot2f(CP, e2_, A4);  A5  = fdot2f(CP, o2_, A5);                        \
    A6  = fdot2f(CP, e3_, A6);  A7  = fdot2f(CP, o3_, A7);                        \
    A8  = fdot2f(CP, e4_, A8);  A9  = fdot2f(CP, o4_, A9);                        \
    A10 = fdot2f(CP, e5_, A10); A11 = fdot2f(CP, o5_, A11);                       \
    A12 = fdot2f(CP, e6_, A12); A13 = fdot2f(CP, o6_, A13);                       \
    A14 = fdot2f(CP, e7_, A14); A15 = fdot2f(CP, o7_, A15);

#define DO_BLOCK(B, x0,x1,x2,x3,x4,x5,x6,x7,x8,x9,x10,x11,x12,x13,x14,x15,x16,x17,x18,x19, \
                    y0,y1,y2,y3,y4,y5,y6,y7,y8,y9,y10,y11,y12,y13,y14)            \
    {                                                                             \
        uint4 cv = *(const uint4*)(SHu + 36 * g + 4 * (B));                       \
        uint4 nw;                                                                 \
        if ((B) < 7) nw = *(const uint4*)(SHu + SLOTU(W0u + 16 + 4 * (B)));       \
        PSTEP(cv.x, x0, x1, x2, x3, x4, x5, x6, x7,  y0, y1, y2, y3, y4, y5, y6, y7)   \
        PSTEP(cv.y, x1, x2, x3, x4, x5, x6, x7, x8,  y1, y2, y3, y4, y5, y6, y7, y8)   \
        PSTEP(cv.z, x2, x3, x4, x5, x6, x7, x8, x9,  y2, y3, y4, y5, y6, y7, y8, y9)   \
        PSTEP(cv.w, x3, x4, x5, x6, x7, x8, x9, x10, y3, y4, y5, y6, y7, y8, y9, y10)  \
        if ((B) < 7) {                                                            \
            x16 = nw.x; x17 = nw.y; x18 = nw.z; x19 = nw.w;                       \
            y11 = AB(x12, x11); y12 = AB(x13, x12);                               \
            y13 = AB(x14, x13); y14 = AB(x15, x14);                               \
        }                                                                         \
    }

    DO_BLOCK(0, aw0,aw1,aw2,aw3,aw4,aw5,aw6,aw7,aw8,aw9,aw10,aw11,aw12,aw13,aw14,aw15,aw16,aw17,aw18,aw19,
                ow0,ow1,ow2,ow3,ow4,ow5,ow6,ow7,ow8,ow9,ow10,ow11,ow12,ow13,ow14)
    DO_BLOCK(1, aw4,aw5,aw6,aw7,aw8,aw9,aw10,aw11,aw12,aw13,aw14,aw15,aw16,aw17,aw18,aw19,aw0,aw1,aw2,aw3,
                ow4,ow5,ow6,ow7,ow8,ow9,ow10,ow11,ow12,ow13,ow14,ow15,ow16,ow17,ow18)
    DO_BLOCK(2, aw8,aw9,aw10,aw11,aw12,aw13,aw14,aw15,aw16,aw17,aw18,aw19,aw0,aw1,aw2,aw3,aw4,aw5,aw6,aw7,
                ow8,ow9,ow10,ow11,ow12,ow13,ow14,ow15,ow16,ow17,ow18,ow19,ow0,ow1,ow2)
    DO_BLOCK(3, aw12,aw13,aw14,aw15,aw16,aw17,aw18,aw19,aw0,aw1,aw2,aw3,aw4,aw5,aw6,aw7,aw8,aw9,aw10,aw11,
                ow12,ow13,ow14,ow15,ow16,ow17,ow18,ow19,ow0,ow1,ow2,ow3,ow4,ow5,ow6)
    DO_BLOCK(4, aw16,aw17,aw18,aw19,aw0,aw1,aw2,aw3,aw4,aw5,aw6,aw7,aw8,aw9,aw10,aw11,aw12,aw13,aw14,aw15,
                ow16,ow17,ow18,ow19,ow0,ow1,ow2,ow3,ow4,ow5,ow6,ow7,ow8,ow9,ow10)
    DO_BLOCK(5, aw0,aw1,aw2,aw3,aw4,aw5,aw6,aw7,aw8,aw9,aw10,aw11,aw12,aw13,aw14,aw15,aw16,aw17,aw18,aw19,
                ow0,ow1,ow2,ow3,ow4,ow5,ow6,ow7,ow8,ow9,ow10,ow11,ow12,ow13,ow14)
    DO_BLOCK(6, aw4,aw5,aw6,aw7,aw8,aw9,aw10,aw11,aw12,aw13,aw14,aw15,aw16,aw17,aw18,aw19,aw0,aw1,aw2,aw3,
                ow4,ow5,ow6,ow7,ow8,ow9,ow10,ow11,ow12,ow13,ow14,ow15,ow16,ow17,ow18)
    DO_BLOCK(7, aw8,aw9,aw10,aw11,aw12,aw13,aw14,aw15,aw16,aw17,aw18,aw19,aw0,aw1,aw2,aw3,aw4,aw5,aw6,aw7,
                ow8,ow9,ow10,ow11,ow12,ow13,ow14,ow15,ow16,ow17,ow18,ow19,ow0,ow1,ow2)
#undef DO_BLOCK
#undef PSTEP

    // ---------------- phase 4: reduce partials over g ----------------------------
    float* PF = SB + PB;
    {
        float4 v4;
        v4.x = A0;  v4.y = A1;  v4.z = A2;  v4.w = A3;
        *(float4*)(PF + 4 * PCHUNK(g, 0, ii)) = v4;
        v4.x = A4;  v4.y = A5;  v4.z = A6;  v4.w = A7;
        *(float4*)(PF + 4 * PCHUNK(g, 1, ii)) = v4;
        v4.x = A8;  v4.y = A9;  v4.z = A10; v4.w = A11;
        *(float4*)(PF + 4 * PCHUNK(g, 2, ii)) = v4;
        v4.x = A12; v4.y = A13; v4.z = A14; v4.w = A15;
        *(float4*)(PF + 4 * PCHUNK(g, 3, ii)) = v4;
    }
    float a0, a1, a2, a3;
    {
        const int iio = lane >> 2, qo = lane & 3;
        float4 u0 = *(const float4*)(PF + 4 * PCHUNK(0, qo, iio));
        float4 u1 = *(const float4*)(PF + 4 * PCHUNK(1, qo, iio));
        float4 u2 = *(const float4*)(PF + 4 * PCHUNK(2, qo, iio));
        float4 u3 = *(const float4*)(PF + 4 * PCHUNK(3, qo, iio));
        a0 = (u0.x + u1.x) + (u2.x + u3.x);
        a1 = (u0.y + u1.y) + (u2.y + u3.y);
        a2 = (u0.z + u1.z) + (u2.z + u3.z);
        a3 = (u0.w + u1.w) + (u2.w + u3.w);
    }
    // lane now owns corr[4l..4l+3]

    // ---------------- phase 5: CMND ----------------------------------------------
    float4 csv  = *(const float4*)(SB + CS_B + 4 * lane);
    float4 csr  = *(const float4*)(SB + CS_B + 252 - 4 * lane);
    float csTop = SB[CS_B + 256 - 4 * lane];

    float d0 = csTop - 2.0f * a0 + totE - csv.x;
    float d1 = csr.w - 2.0f * a1 + totE - csv.y;
    float d2 = csr.z - 2.0f * a2 + totE - csv.z;
    float d3 = csr.y - 2.0f * a3 + totE - csv.w;
    if (lane == 0) d0 = 0.0f;                 // diff[0] excluded from prefix
    float l0 = d0, l1 = l0 + d1, l2 = l1 + d2, l3 = l2 + d3;
    float scn = l3;
#pragma unroll
    for (int off = 1; off < 64; off <<= 1) {
        float o = __shfl_up(scn, off);
        if (lane >= off) scn += o;
    }
    float pb = scn - l3;
    const int t0 = 4 * lane;
    float cd0 = d0 * (float)(t0 + 0) / (pb + l0 + 1e-7f);
    float cd1 = d1 * (float)(t0 + 1) / (pb + l1 + 1e-7f);
    float cd2 = d2 * (float)(t0 + 2) / (pb + l2 + 1e-7f);
    float cd3 = d3 * (float)(t0 + 3) / (pb + l3 + 1e-7f);
    if (lane <= 53) {                          // taus 0..215 (>=213 junk, never used)
        float4 cdv;
        cdv.x = (lane == 0) ? 1.0f : cd0;
        cdv.y = cd1; cdv.z = cd2; cdv.w = cd3;
        *(float4*)(SB + CM_B + t0) = cdv;
    }

    // ---------------- phase 6: threshold + tau searches via ballot ---------------
    // cmnd[i] = SB[CM_B + 26 + i], i in [0,187). Junk beyond masked.
    const float am0  = SB[CM_B + 25 + lane];
    const float bm0  = SB[CM_B + 26 + lane];
    const float cn0  = SB[CM_B + 27 + lane];
    const float am1  = SB[CM_B + 25 + 64 + lane];
    const float bm1  = SB[CM_B + 26 + 64 + lane];
    const float cn1  = SB[CM_B + 27 + 64 + lane];
    const float am2  = SB[CM_B + 25 + 128 + lane];
    const float bm2  = SB[CM_B + 26 + 128 + lane];
    const float cn2  = SB[CM_B + 27 + 128 + lane];

    unsigned long long tm0 = __ballot((lane < 187)       && (bm0 < 0.1f));
    unsigned long long tm1 = __ballot((64 + lane < 187)  && (bm1 < 0.1f));
    unsigned long long tm2 = __ballot((128 + lane < 187) && (bm2 < 0.1f));
    int cand = tm0 ? (__ffsll(tm0) - 1)
             : (tm1 ? (64 + __ffsll(tm1) - 1)
             : (tm2 ? (128 + __ffsll(tm2) - 1) : 999));
    const int thold = (cand == 0 || cand == 999) ? C_LEN : cand;

    const int i0 = lane, i1 = 64 + lane, i2 = 128 + lane;
    bool L0 = (i0 == 0)   || (bm0 - am0 <= 0.0f);
    bool R0 = (i0 == 186) || (cn0 - bm0 >= 0.0f);
    bool L1 = (bm1 - am1 <= 0.0f);
    bool R1 = (cn1 - bm1 >= 0.0f);
    bool L2 = (bm2 - am2 <= 0.0f);
    bool R2 = (i2 == 186) || (cn2 - bm2 >= 0.0f);
    unsigned long long lm0 = __ballot((i0 >= thold) && (i0 < C_LEN) && L0 && R0);
    unsigned long long lm1 = __ballot((i1 >= thold) && (i1 < C_LEN) && L1 && R1);
    unsigned long long lm2 = __ballot((i2 >= thold) && (i2 < C_LEN) && L2 && R2);
    int tcand = lm0 ? (__ffsll(lm0) - 1)
              : (lm1 ? (64 + __ffsll(lm1) - 1)
              : (lm2 ? (128 + __ffsll(lm2) - 1) : 999));
    const int tau = (tcand == 999) ? 0 : tcand;

    // ---------------- phase 7: parabolic interp + pitch --------------------------
    float pv = 0.0f;
    if (tau > 0) {
        float shift = 0.0f;
        if (tau <= C_LEN - 2) {
            float pp = SB[CM_B + 26 + tau - 1];
            float cc = SB[CM_B + 26 + tau];
            float nn = SB[CM_B + 26 + tau + 1];
            float aa = nn + pp - 2.0f * cc;
            float bb = 0.5f * (nn - pp);
            shift = (fabsf(bb) >= fabsf(aa)) ? 0.0f : (-bb / aa);
        }
        pv = 16000.0f / ((float)(tau + TAU_MINC + 1) + shift);
    }
    if (lane == 0) pitch[frame] = pv;
}

// 30-wide median (index 14 of ascending sort), edge-padded (15,14).
// Fully unrolled selection so v[] stays in registers.
__global__ __launch_bounds__(256) void median_k(const float* __restrict__ pitch,
                                                float* __restrict__ out) {
    int idx = blockIdx.x * blockDim.x + threadIdx.x;
    if (idx >= NFRAMES) return;
    int b = idx / NF;
    int f = idx - b * NF;
    const float* p = pitch + b * NF;
    float v[30];
#pragma unroll
    for (int k = 0; k < 30; ++k) {
        int j = f + k - 15;
        j = (j < 0) ? 0 : ((j > NF - 1) ? NF - 1 : j);
        v[k] = p[j];
    }
    float result = 0.0f;
#pragma unroll
    for (int i = 0; i < 30; ++i) {
        int lt = 0, le = 0;
#pragma unroll
        for (int j = 0; j < 30; ++j) {
            lt += (v[j] < v[i]);
            le += (v[j] <= v[i]);
        }
        if (lt <= 14 && 14 < le) result = v[i];
    }
    out[idx] = result;
}

extern "C" void kernel_launch(void* const* d_in, const int* in_sizes, int n_in,
                              void* d_out, int out_size, void* d_ws, size_t ws_size,
                              hipStream_t stream) {
    (void)in_sizes; (void)n_in; (void)out_size; (void)ws_size;
    const float* in = (const float*)d_in[0];
    float* out = (float*)d_out;
    float* pitch = (float*)d_ws;     // NFRAMES floats = 256 KB scratch

    yin_frames<<<NFRAMES / 2, 128, 0, stream>>>(in, pitch);
    median_k<<<(NFRAMES + 255) / 256, 256, 0, stream>>>(pitch, out);
}

// Round 9
// 107.855 us; speedup vs baseline: 11.9314x; 1.0358x over previous
//
#include <hip/hip_runtime.h>
#include <math.h>

// YIN pitch, MI355X. Constants from reference:
//   SR=16000, STRIDES=160, W=257, TAU_MAX=213, TAU_MIN=26, C=187, MEDIAN=30
#define T_LEN    160000
#define STRIDES  160
#define NF       1001
#define NB       64
#define TAU_MINC 26
#define C_LEN    187
#define NFRAMES  (NB * NF)     // 64064

// Per-wave LDS map (floats). Sequential lifetimes (wave-synchronous):
//   [0,292)    SH: f16 signal, 292 padded u32. Dead after phase 3.
//   [0,584)    part: phase-4 partials (2 groups after shfl pre-reduce). Aliases SH.
//   [0,216)    CM: cmnd, aliases part after part reads.
//   [584,841)  CS: cumsum of squares, 257 floats.
#define WAVE_F  848
#define CS_B    584
#define CM_B    0
#define PCHUNK2(gg, q, ii) ((gg) * 73 + (q) * 18 + (ii))   // chunk idx, max 142

// Padded u32 index for the f16 signal: one 16B chunk inserted every 32 u32 so
// the 16 ii-lanes' window reads (u32 stride 8) spread across bank-quads.
#define SLOTU(U) ((U) + 4 * ((U) >> 5))

// clang's AMDGPU builtins use __fp16 vectors:
//   __builtin_amdgcn_cvt_pkrtz : (float,float) -> V2h
//   __builtin_amdgcn_fdot2     : (V2h, V2h, float, bool) -> float
typedef __fp16 half2_t __attribute__((ext_vector_type(2)));
union H2U { half2_t h; unsigned int u; };

__device__ __forceinline__ unsigned int pack2h(float a, float b) {
    H2U x;
#if __has_builtin(__builtin_amdgcn_cvt_pkrtz)
    x.h = __builtin_amdgcn_cvt_pkrtz(a, b);
#else
    x.h.x = (__fp16)a; x.h.y = (__fp16)b;
#endif
    return x.u;
}

__device__ __forceinline__ float fdot2f(unsigned int a, unsigned int b, float c) {
    H2U ua, ub; ua.u = a; ub.u = b;
#if __has_builtin(__builtin_amdgcn_fdot2)
    return __builtin_amdgcn_fdot2(ua.h, ub.h, c, false);
#else
    return c + (float)ua.h.x * (float)ub.h.x + (float)ua.h.y * (float)ub.h.y;
#endif
}

__device__ __forceinline__ float loH(unsigned int u) { H2U t; t.u = u; return (float)t.h.x; }
__device__ __forceinline__ float hiH(unsigned int u) { H2U t; t.u = u; return (float)t.h.y; }

__device__ __forceinline__ float frcp(float x) {
#if __has_builtin(__builtin_amdgcn_rcpf)
    return __builtin_amdgcn_rcpf(x);
#else
    return 1.0f / x;
#endif
}

// odd-pair from two aligned pairs: (halfs 2i+1, 2i+2)
#define AB(HI, LO) ((unsigned int)(((LO) >> 16) | ((HI) << 16)))

// R2-R4 lesson: arrays with computed indices survive SROA as allocas ->
// scratch -> 6 GB HBM. Hot loop uses ONLY named scalars (proven R5/R6/R8).

__global__ __launch_bounds__(128, 7) void yin_frames(const float* __restrict__ in,
                                                     float* __restrict__ pitch) {
    __shared__ __align__(16) float SB_[2][WAVE_F];

    const int wid  = threadIdx.x >> 6;
    const int lane = threadIdx.x & 63;
    const int frame = blockIdx.x * 2 + wid;
    const int b = frame / NF;
    const int f = frame - b * NF;
    float* SB = SB_[wid];
    unsigned int* SHu = (unsigned int*)SB;

    // ---------------- phase 1: zero padded f16 region + stage frame --------------
    {
        uint4 z; z.x = 0u; z.y = 0u; z.z = 0u; z.w = 0u;
        *(uint4*)(SHu + 4 * lane) = z;                      // u32 [0,256)
        if (lane < 9) *(uint4*)(SHu + 256 + 4 * lane) = z;  // u32 [256,292)
    }
    const float* src = in + (size_t)b * T_LEN;
    const int start = f * STRIDES;
    int e0 = start + 4 * lane;
    float4 q;
    if (e0 + 3 < T_LEN) {
        q = *(const float4*)(src + e0);
    } else {
        q.x = (e0 + 0 < T_LEN) ? src[e0 + 0] : 0.f;
        q.y = (e0 + 1 < T_LEN) ? src[e0 + 1] : 0.f;
        q.z = (e0 + 2 < T_LEN) ? src[e0 + 2] : 0.f;
        q.w = (e0 + 3 < T_LEN) ? src[e0 + 3] : 0.f;
    }
    {   // halfs 4l..4l+3 at padded u32 2l; pair doesn't cross a pad chunk
        uint2 d; d.x = pack2h(q.x, q.y); d.y = pack2h(q.z, q.w);
        *(uint2*)(SHu + 2 * lane + 4 * (lane >> 4)) = d;
    }
    float s256f = 0.0f;
    if (lane == 0) {
        int e2 = start + 256;
        s256f = (e2 < T_LEN) ? src[e2] : 0.f;
        SHu[SLOTU(128)] = pack2h(s256f, 0.f);               // halfs 256,257
    }
    s256f = __shfl(s256f, 0);

    // ---------------- phase 2: cumsum of squares (fp32, wave scan) ---------------
    float p0 = q.x * q.x;
    float p1 = p0 + q.y * q.y;
    float p2 = p1 + q.z * q.z;
    float p3 = p2 + q.w * q.w;
    float sc = p3;
#pragma unroll
    for (int off = 1; off < 64; off <<= 1) {
        float o = __shfl_up(sc, off);
        if (lane >= off) sc += o;
    }
    {
        float base = sc - p3;
        float4 csw;
        csw.x = base + p0; csw.y = base + p1; csw.z = base + p2; csw.w = base + p3;
        *(float4*)(SB + CS_B + 4 * lane) = csw;             // park cs[] in LDS
    }
    float totE = __shfl(sc, 63) + s256f * s256f;
    if (lane == 63) SB[CS_B + 256] = totE;

    // ---------------- phase 3: autocorr via v_dot2_f32_f16 -----------------------
    // lane = (g,ii): g covers j in [64g,64g+64), ii covers taus 16ii..16ii+15.
    // Even tau 2e:  dot2(c_aligned_p, w_{p+e});  covers j in [64g, 64g+64).
    // Odd tau 2e+1: dot2(c_odd_p, w_{p+e+1});   covers j in [64g+1, 64g+65) --
    //   telescopes over g to [1,257); the missing x[0]*x[tau] term is added as
    //   the odd accumulators' init (g==0 lanes only). c_odd built by 4 alignbits
    //   per block (shared by all 16 A's) -- no persistent odd window file.
    const int g  = lane >> 4;
    const int ii = lane & 15;
    const int W0u = 32 * g + 8 * ii;                        // unpadded u32 window base
    const int cb  = 36 * g;                                 // padded u32 base of c region

    unsigned int aw0, aw1, aw2, aw3, aw4, aw5, aw6, aw7, aw8, aw9;
    unsigned int aw10, aw11, aw12, aw13, aw14, aw15, aw16, aw17, aw18, aw19;
    {
        uint4 t;
        t = *(const uint4*)(SHu + SLOTU(W0u + 0));  aw0  = t.x; aw1  = t.y; aw2  = t.z; aw3  = t.w;
        t = *(const uint4*)(SHu + SLOTU(W0u + 4));  aw4  = t.x; aw5  = t.y; aw6  = t.z; aw7  = t.w;
        t = *(const uint4*)(SHu + SLOTU(W0u + 8));  aw8  = t.x; aw9  = t.y; aw10 = t.z; aw11 = t.w;
        t = *(const uint4*)(SHu + SLOTU(W0u + 12)); aw12 = t.x; aw13 = t.y; aw14 = t.z; aw15 = t.w;
        t = *(const uint4*)(SHu + SLOTU(W0u + 16)); aw16 = t.x; aw17 = t.y; aw18 = t.z; aw19 = t.w;
    }
    uint4 cvq = *(const uint4*)(SHu + cb);

    // odd-A init = missing j=0 term (g==0 lanes only); evens init 0.
    const float x0f = loH(SHu[0]);
    const bool g0 = (g == 0);
    float A0 = 0.f,                                A1  = g0 ? x0f * hiH(aw0) : 0.f;
    float A2 = 0.f,                                A3  = g0 ? x0f * hiH(aw1) : 0.f;
    float A4 = 0.f,                                A5  = g0 ? x0f * hiH(aw2) : 0.f;
    float A6 = 0.f,                                A7  = g0 ? x0f * hiH(aw3) : 0.f;
    float A8 = 0.f,                                A9  = g0 ? x0f * hiH(aw4) : 0.f;
    float A10 = 0.f,                               A11 = g0 ? x0f * hiH(aw5) : 0.f;
    float A12 = 0.f,                               A13 = g0 ? x0f * hiH(aw6) : 0.f;
    float A14 = 0.f,                               A15 = g0 ? x0f * hiH(aw7) : 0.f;

// A_{2e} += dot2(CA, X_{e}); A_{2e+1} += dot2(CO, X_{e+1})
#define PSTEP(CA, CO, X0, X1, X2, X3, X4, X5, X6, X7, X8)                        \
    A0  = fdot2f(CA, X0, A0);   A1  = fdot2f(CO, X1, A1);                        \
    A2  = fdot2f(CA, X1, A2);   A3  = fdot2f(CO, X2, A3);                        \
    A4  = fdot2f(CA, X2, A4);   A5  = fdot2f(CO, X3, A5);                        \
    A6  = fdot2f(CA, X3, A6);   A7  = fdot2f(CO, X4, A7);                        \
    A8  = fdot2f(CA, X4, A8);   A9  = fdot2f(CO, X5, A9);                        \
    A10 = fdot2f(CA, X5, A10);  A11 = fdot2f(CO, X6, A11);                       \
    A12 = fdot2f(CA, X6, A12);  A13 = fdot2f(CO, X7, A13);                       \
    A14 = fdot2f(CA, X7, A14);  A15 = fdot2f(CO, X8, A15);

#define DO_BLOCK(B, p0_,p1_,p2_,p3_,p4_,p5_,p6_,p7_,p8_,p9_,p10_,p11_,p12_,p13_,p14_,p15_,p16_,p17_,p18_,p19_) \
    {                                                                             \
        const unsigned int ca0 = cvq.x, ca1 = cvq.y, ca2 = cvq.z, ca3 = cvq.w;    \
        uint4 ncq, nwq; unsigned int c8v = 0;                                     \
        if ((B) < 7) {                                                            \
            ncq = *(const uint4*)(SHu + cb + 4 * (B) + 4);                        \
            nwq = *(const uint4*)(SHu + SLOTU(W0u + 20 + 4 * (B)));               \
        } else {                                                                  \
            c8v = SHu[cb + 36];                                                   \
        }                                                                         \
        const unsigned int co0 = AB(ca1, ca0);                                    \
        const unsigned int co1 = AB(ca2, ca1);                                    \
        const unsigned int co2 = AB(ca3, ca2);                                    \
        const unsigned int co3 = AB(((B) < 7) ? ncq.x : c8v, ca3);                \
        PSTEP(ca0, co0, p0_, p1_, p2_, p3_, p4_, p5_, p6_, p7_, p8_)              \
        PSTEP(ca1, co1, p1_, p2_, p3_, p4_, p5_, p6_, p7_, p8_, p9_)              \
        PSTEP(ca2, co2, p2_, p3_, p4_, p5_, p6_, p7_, p8_, p9_, p10_)             \
        PSTEP(ca3, co3, p3_, p4_, p5_, p6_, p7_, p8_, p9_, p10_, p11_)            \
        if ((B) < 7) {                                                            \
            p16_ = nwq.x; p17_ = nwq.y; p18_ = nwq.z; p19_ = nwq.w;               \
            cvq = ncq;                                                            \
        }                                                                         \
    }

    DO_BLOCK(0, aw0,aw1,aw2,aw3,aw4,aw5,aw6,aw7,aw8,aw9,aw10,aw11,aw12,aw13,aw14,aw15,aw16,aw17,aw18,aw19)
    DO_BLOCK(1, aw4,aw5,aw6,aw7,aw8,aw9,aw10,aw11,aw12,aw13,aw14,aw15,aw16,aw17,aw18,aw19,aw0,aw1,aw2,aw3)
    DO_BLOCK(2, aw8,aw9,aw10,aw11,aw12,aw13,aw14,aw15,aw16,aw17,aw18,aw19,aw0,aw1,aw2,aw3,aw4,aw5,aw6,aw7)
    DO_BLOCK(3, aw12,aw13,aw14,aw15,aw16,aw17,aw18,aw19,aw0,aw1,aw2,aw3,aw4,aw5,aw6,aw7,aw8,aw9,aw10,aw11)
    DO_BLOCK(4, aw16,aw17,aw18,aw19,aw0,aw1,aw2,aw3,aw4,aw5,aw6,aw7,aw8,aw9,aw10,aw11,aw12,aw13,aw14,aw15)
    DO_BLOCK(5, aw0,aw1,aw2,aw3,aw4,aw5,aw6,aw7,aw8,aw9,aw10,aw11,aw12,aw13,aw14,aw15,aw16,aw17,aw18,aw19)
    DO_BLOCK(6, aw4,aw5,aw6,aw7,aw8,aw9,aw10,aw11,aw12,aw13,aw14,aw15,aw16,aw17,aw18,aw19,aw0,aw1,aw2,aw3)
    DO_BLOCK(7, aw8,aw9,aw10,aw11,aw12,aw13,aw14,aw15,aw16,aw17,aw18,aw19,aw0,aw1,aw2,aw3,aw4,aw5,aw6,aw7)
#undef DO_BLOCK
#undef PSTEP

    // ---------------- phase 4: reduce partials over g ----------------------------
    // Pre-reduce g pairs in registers (g <-> g^2), then 2-group LDS roundtrip.
#define RED32(K) A##K += __shfl_xor(A##K, 32);
    RED32(0)  RED32(1)  RED32(2)  RED32(3)  RED32(4)  RED32(5)  RED32(6)  RED32(7)
    RED32(8)  RED32(9)  RED32(10) RED32(11) RED32(12) RED32(13) RED32(14) RED32(15)
#undef RED32
    if (lane < 32) {                      // gg = g&1 in {0,1}
        const int gg = lane >> 4;
        const int iw = lane & 15;
        float4 v4;
        v4.x = A0;  v4.y = A1;  v4.z = A2;  v4.w = A3;
        *(float4*)(SB + 4 * PCHUNK2(gg, 0, iw)) = v4;
        v4.x = A4;  v4.y = A5;  v4.z = A6;  v4.w = A7;
        *(float4*)(SB + 4 * PCHUNK2(gg, 1, iw)) = v4;
        v4.x = A8;  v4.y = A9;  v4.z = A10; v4.w = A11;
        *(float4*)(SB + 4 * PCHUNK2(gg, 2, iw)) = v4;
        v4.x = A12; v4.y = A13; v4.z = A14; v4.w = A15;
        *(float4*)(SB + 4 * PCHUNK2(gg, 3, iw)) = v4;
    }
    float a0, a1, a2, a3;
    {
        const int iio = lane >> 2, qo = lane & 3;
        float4 u0 = *(const float4*)(SB + 4 * PCHUNK2(0, qo, iio));
        float4 u1 = *(const float4*)(SB + 4 * PCHUNK2(1, qo, iio));
        a0 = u0.x + u1.x;
        a1 = u0.y + u1.y;
        a2 = u0.z + u1.z;
        a3 = u0.w + u1.w;
    }
    // lane now owns corr[4l..4l+3]

    // ---------------- phase 5: CMND ----------------------------------------------
    float4 csv  = *(const float4*)(SB + CS_B + 4 * lane);
    float4 csr  = *(const float4*)(SB + CS_B + 252 - 4 * lane);
    float csTop = SB[CS_B + 256 - 4 * lane];

    float d0 = csTop - 2.0f * a0 + totE - csv.x;
    float d1 = csr.w - 2.0f * a1 + totE - csv.y;
    float d2 = csr.z - 2.0f * a2 + totE - csv.z;
    float d3 = csr.y - 2.0f * a3 + totE - csv.w;
    if (lane == 0) d0 = 0.0f;                 // diff[0] excluded from prefix
    float l0 = d0, l1 = l0 + d1, l2 = l1 + d2, l3 = l2 + d3;
    float scn = l3;
#pragma unroll
    for (int off = 1; off < 64; off <<= 1) {
        float o = __shfl_up(scn, off);
        if (lane >= off) scn += o;
    }
    float pb = scn - l3;
    const int t0 = 4 * lane;
    float cd0 = d0 * (float)(t0 + 0) * frcp(pb + l0 + 1e-7f);
    float cd1 = d1 * (float)(t0 + 1) * frcp(pb + l1 + 1e-7f);
    float cd2 = d2 * (float)(t0 + 2) * frcp(pb + l2 + 1e-7f);
    float cd3 = d3 * (float)(t0 + 3) * frcp(pb + l3 + 1e-7f);
    if (lane <= 53) {                          // taus 0..215 (>=213 junk, never used)
        float4 cdv;
        cdv.x = (lane == 0) ? 1.0f : cd0;
        cdv.y = cd1; cdv.z = cd2; cdv.w = cd3;
        *(float4*)(SB + CM_B + t0) = cdv;
    }

    // ---------------- phase 6: threshold + tau searches via ballot ---------------
    // cmnd[i] = SB[CM_B + 26 + i], i in [0,187). Junk beyond masked.
    const float am0  = SB[CM_B + 25 + lane];
    const float bm0  = SB[CM_B + 26 + lane];
    const float cn0  = SB[CM_B + 27 + lane];
    const float am1  = SB[CM_B + 25 + 64 + lane];
    const float bm1  = SB[CM_B + 26 + 64 + lane];
    const float cn1  = SB[CM_B + 27 + 64 + lane];
    const float am2  = SB[CM_B + 25 + 128 + lane];
    const float bm2  = SB[CM_B + 26 + 128 + lane];
    const float cn2  = SB[CM_B + 27 + 128 + lane];

    unsigned long long tm0 = __ballot((lane < 187)       && (bm0 < 0.1f));
    unsigned long long tm1 = __ballot((64 + lane < 187)  && (bm1 < 0.1f));
    unsigned long long tm2 = __ballot((128 + lane < 187) && (bm2 < 0.1f));
    int cand = tm0 ? (__ffsll(tm0) - 1)
             : (tm1 ? (64 + __ffsll(tm1) - 1)
             : (tm2 ? (128 + __ffsll(tm2) - 1) : 999));
    const int thold = (cand == 0 || cand == 999) ? C_LEN : cand;

    const int i0 = lane, i1 = 64 + lane, i2 = 128 + lane;
    bool L0 = (i0 == 0)   || (bm0 - am0 <= 0.0f);
    bool R0 = (i0 == 186) || (cn0 - bm0 >= 0.0f);
    bool L1 = (bm1 - am1 <= 0.0f);
    bool R1 = (cn1 - bm1 >= 0.0f);
    bool L2 = (bm2 - am2 <= 0.0f);
    bool R2 = (i2 == 186) || (cn2 - bm2 >= 0.0f);
    unsigned long long lm0 = __ballot((i0 >= thold) && (i0 < C_LEN) && L0 && R0);
    unsigned long long lm1 = __ballot((i1 >= thold) && (i1 < C_LEN) && L1 && R1);
    unsigned long long lm2 = __ballot((i2 >= thold) && (i2 < C_LEN) && L2 && R2);
    int tcand = lm0 ? (__ffsll(lm0) - 1)
              : (lm1 ? (64 + __ffsll(lm1) - 1)
              : (lm2 ? (128 + __ffsll(lm2) - 1) : 999));
    const int tau = (tcand == 999) ? 0 : tcand;

    // ---------------- phase 7: parabolic interp + pitch --------------------------
    float pv = 0.0f;
    if (tau > 0) {
        float shift = 0.0f;
        if (tau <= C_LEN - 2) {
            float pp = SB[CM_B + 26 + tau - 1];
            float cc = SB[CM_B + 26 + tau];
            float nn = SB[CM_B + 26 + tau + 1];
            float aa = nn + pp - 2.0f * cc;
            float bb = 0.5f * (nn - pp);
            shift = (fabsf(bb) >= fabsf(aa)) ? 0.0f : (-bb / aa);
        }
        pv = 16000.0f / ((float)(tau + TAU_MINC + 1) + shift);
    }
    if (lane == 0) pitch[frame] = pv;
}

// 30-wide median (index 14 of ascending sort), edge-padded (15,14).
// Fully unrolled selection so v[] stays in registers.
__global__ __launch_bounds__(256) void median_k(const float* __restrict__ pitch,
                                                float* __restrict__ out) {
    int idx = blockIdx.x * blockDim.x + threadIdx.x;
    if (idx >= NFRAMES) return;
    int b = idx / NF;
    int f = idx - b * NF;
    const float* p = pitch + b * NF;
    float v[30];
#pragma unroll
    for (int k = 0; k < 30; ++k) {
        int j = f + k - 15;
        j = (j < 0) ? 0 : ((j > NF - 1) ? NF - 1 : j);
        v[k] = p[j];
    }
    float result = 0.0f;
#pragma unroll
    for (int i = 0; i < 30; ++i) {
        int lt = 0, le = 0;
#pragma unroll
        for (int j = 0; j < 30; ++j) {
            lt += (v[j] < v[i]);
            le += (v[j] <= v[i]);
        }
        if (lt <= 14 && 14 < le) result = v[i];
    }
    out[idx] = result;
}

extern "C" void kernel_launch(void* const* d_in, const int* in_sizes, int n_in,
                              void* d_out, int out_size, void* d_ws, size_t ws_size,
                              hipStream_t stream) {
    (void)in_sizes; (void)n_in; (void)out_size; (void)ws_size;
    const float* in = (const float*)d_in[0];
    float* out = (float*)d_out;
    float* pitch = (float*)d_ws;     // NFRAMES floats = 256 KB scratch

    yin_frames<<<NFRAMES / 2, 128, 0, stream>>>(in, pitch);
    median_k<<<(NFRAMES + 255) / 256, 256, 0, stream>>>(pitch, out);
}